// Round 1
// baseline (13718.137 us; speedup 1.0000x reference)
//
#include <hip/hip_runtime.h>
#include <hip/hip_bf16.h>
#include <math.h>

// Problem constants
#define BB 4
#define NN 1024
#define MM 512
#define DD 512
#define PP 256
#define HH 8
#define DHH 64
#define LL 6
#define FFI 2048

// ---------------------------------------------------------------------------
// LayerNorm: y[row] = LN(x[row]) * g (+ resid[row]); stable => x /= max(x) first
// ---------------------------------------------------------------------------
__global__ __launch_bounds__(256) void ln_kernel(const float* __restrict__ x,
                                                 const float* __restrict__ g,
                                                 const float* __restrict__ resid,
                                                 float* __restrict__ y,
                                                 int cols, int stable) {
  __shared__ float sbuf[8];
  int row = blockIdx.x;
  const float* xr = x + (size_t)row * cols;
  int tid = threadIdx.x;

  float inv_mx = 1.f;
  if (stable) {
    float mx = -INFINITY;
    for (int c = tid; c < cols; c += 256) mx = fmaxf(mx, xr[c]);
    #pragma unroll
    for (int o = 32; o > 0; o >>= 1) mx = fmaxf(mx, __shfl_xor(mx, o));
    if ((tid & 63) == 0) sbuf[tid >> 6] = mx;
    __syncthreads();
    mx = fmaxf(fmaxf(sbuf[0], sbuf[1]), fmaxf(sbuf[2], sbuf[3]));
    __syncthreads();
    inv_mx = 1.f / mx;
  }

  float sum = 0.f, ss = 0.f;
  for (int c = tid; c < cols; c += 256) {
    float v = xr[c] * inv_mx;
    sum += v; ss += v * v;
  }
  #pragma unroll
  for (int o = 32; o > 0; o >>= 1) { sum += __shfl_xor(sum, o); ss += __shfl_xor(ss, o); }
  if ((tid & 63) == 0) { sbuf[tid >> 6] = sum; sbuf[4 + (tid >> 6)] = ss; }
  __syncthreads();
  sum = sbuf[0] + sbuf[1] + sbuf[2] + sbuf[3];
  ss  = sbuf[4] + sbuf[5] + sbuf[6] + sbuf[7];

  float mean = sum / cols;
  float var  = ss / cols - mean * mean;
  float r = rsqrtf(var + 1e-5f);
  for (int c = tid; c < cols; c += 256) {
    float v = (xr[c] * inv_mx - mean) * r * g[c];
    if (resid) v += resid[(size_t)row * cols + c];
    y[(size_t)row * cols + c] = v;
  }
}

// ---------------------------------------------------------------------------
// fp32 tiled GEMM: C(MxN) = A(MxK) @ B(KxN) [+ res]; all dims %64==0 (K%16)
// ---------------------------------------------------------------------------
#define GTM 64
#define GTN 64
#define GTK 16
__global__ __launch_bounds__(256) void gemm_kernel(const float* __restrict__ A,
                                                   const float* __restrict__ B,
                                                   float* __restrict__ C,
                                                   const float* __restrict__ res,
                                                   int M, int N, int K) {
  __shared__ float As[GTK][GTM + 1];
  __shared__ float Bs[GTK][GTN];
  int tid = threadIdx.x;
  int bm = blockIdx.y * GTM, bn = blockIdx.x * GTN;
  int tx = tid & 15, ty = tid >> 4;
  float acc[4][4] = {};

  for (int k0 = 0; k0 < K; k0 += GTK) {
    #pragma unroll
    for (int i = 0; i < 4; i++) {
      int idx = tid + i * 256;
      int m = idx >> 4, kk = idx & 15;
      As[kk][m] = A[(size_t)(bm + m) * K + k0 + kk];
    }
    #pragma unroll
    for (int i = 0; i < 4; i++) {
      int idx = tid + i * 256;
      int kk2 = idx >> 6, n = idx & 63;
      Bs[kk2][n] = B[(size_t)(k0 + kk2) * N + bn + n];
    }
    __syncthreads();
    #pragma unroll
    for (int kk = 0; kk < GTK; kk++) {
      float a[4], b[4];
      #pragma unroll
      for (int i = 0; i < 4; i++) a[i] = As[kk][ty * 4 + i];
      #pragma unroll
      for (int j = 0; j < 4; j++) b[j] = Bs[kk][tx * 4 + j];
      #pragma unroll
      for (int i = 0; i < 4; i++)
        #pragma unroll
        for (int j = 0; j < 4; j++) acc[i][j] += a[i] * b[j];
    }
    __syncthreads();
  }

  #pragma unroll
  for (int i = 0; i < 4; i++) {
    int m = bm + ty * 4 + i;
    #pragma unroll
    for (int j = 0; j < 4; j++) {
      int n = bn + tx * 4 + j;
      float v = acc[i][j];
      if (res) v += res[(size_t)m * N + n];
      C[(size_t)m * N + n] = v;
    }
  }
}

// ---------------------------------------------------------------------------
// Gated FF GEMM: W is K x 2*FI. C[m][n] = h * silu(gate),
//   h = (A@W)[m][n], gate = (A@W)[m][n+FI].  Output C is M x FI.
// ---------------------------------------------------------------------------
__global__ __launch_bounds__(256) void gemm_gated_kernel(const float* __restrict__ A,
                                                         const float* __restrict__ B,
                                                         float* __restrict__ C,
                                                         int M, int FIc, int K) {
  __shared__ float As[GTK][GTM + 1];
  __shared__ float Bs1[GTK][GTN];
  __shared__ float Bs2[GTK][GTN];
  int tid = threadIdx.x;
  int bm = blockIdx.y * GTM, bn = blockIdx.x * GTN;
  int tx = tid & 15, ty = tid >> 4;
  int ldb = 2 * FIc;
  float acc1[4][4] = {};
  float acc2[4][4] = {};

  for (int k0 = 0; k0 < K; k0 += GTK) {
    #pragma unroll
    for (int i = 0; i < 4; i++) {
      int idx = tid + i * 256;
      int m = idx >> 4, kk = idx & 15;
      As[kk][m] = A[(size_t)(bm + m) * K + k0 + kk];
    }
    #pragma unroll
    for (int i = 0; i < 4; i++) {
      int idx = tid + i * 256;
      int kk2 = idx >> 6, n = idx & 63;
      Bs1[kk2][n] = B[(size_t)(k0 + kk2) * ldb + bn + n];
      Bs2[kk2][n] = B[(size_t)(k0 + kk2) * ldb + FIc + bn + n];
    }
    __syncthreads();
    #pragma unroll
    for (int kk = 0; kk < GTK; kk++) {
      float a[4], b1[4], b2[4];
      #pragma unroll
      for (int i = 0; i < 4; i++) a[i] = As[kk][ty * 4 + i];
      #pragma unroll
      for (int j = 0; j < 4; j++) { b1[j] = Bs1[kk][tx * 4 + j]; b2[j] = Bs2[kk][tx * 4 + j]; }
      #pragma unroll
      for (int i = 0; i < 4; i++)
        #pragma unroll
        for (int j = 0; j < 4; j++) { acc1[i][j] += a[i] * b1[j]; acc2[i][j] += a[i] * b2[j]; }
    }
    __syncthreads();
  }

  #pragma unroll
  for (int i = 0; i < 4; i++) {
    int m = bm + ty * 4 + i;
    #pragma unroll
    for (int j = 0; j < 4; j++) {
      int n = bn + tx * 4 + j;
      float h = acc1[i][j], gt = acc2[i][j];
      float sg = 1.f / (1.f + expf(-gt));
      C[(size_t)m * FIc + n] = h * gt * sg;
    }
  }
}

// ---------------------------------------------------------------------------
// Q prep: q[b][h][i][d] = rotary?(q_lin[b][i][h*64+d] * 0.125)
// ---------------------------------------------------------------------------
__global__ __launch_bounds__(256) void qprep_kernel(const float* __restrict__ q_lin,
                                                    float* __restrict__ q, int use_rot) {
  int idx = blockIdx.x * 256 + threadIdx.x;   // ((b*8+h)*1024+i)*64+d
  int d = idx & 63;
  int i = (idx >> 6) & 1023;
  int h = (idx >> 16) & 7;
  int b = idx >> 19;
  const float* src = q_lin + ((size_t)(b * NN + i)) * DD + h * DHH;
  float val = src[d] * 0.125f;
  if (use_rot && d < 32) {
    int dd = d & 15;
    float inv = powf(10000.f, -(float)dd * (1.f / 16.f));
    float a = (float)i * inv;
    float other = src[(d < 16) ? d + 16 : d - 16] * 0.125f;
    val = val * cosf(a) + ((d < 16) ? -other : other) * sinf(a);
  }
  q[idx] = val;
}

// ---------------------------------------------------------------------------
// KV prep: prepend null kv at j=0; rotary on k (self-attn only).
// kv_lin: (B, NT, 128); k,v out: (B, NK, 64), NK = NT+1
// grid = NK blocks of 256 (B*NK*64 == 256*NK)
// ---------------------------------------------------------------------------
__global__ __launch_bounds__(256) void kvprep_kernel(const float* __restrict__ kv_lin,
                                                     const float* __restrict__ null_kv,
                                                     float* __restrict__ k, float* __restrict__ v,
                                                     int NK, int NT, int use_rot) {
  int idx = blockIdx.x * 256 + threadIdx.x;
  int d = idx & 63;
  int j = (idx >> 6) % NK;
  int b = idx / (NK * 64);
  float kval, vval;
  if (j == 0) {
    kval = null_kv[d];
    vval = null_kv[64 + d];
  } else {
    int t = j - 1;
    const float* src = kv_lin + ((size_t)(b * NT + t)) * 128;
    kval = src[d];
    vval = src[64 + d];
    if (use_rot && d < 32) {
      int dd = d & 15;
      float inv = powf(10000.f, -(float)dd * (1.f / 16.f));
      float a = (float)t * inv;
      float other = src[(d < 16) ? d + 16 : d - 16];
      kval = kval * cosf(a) + ((d < 16) ? -other : other) * sinf(a);
    }
  }
  k[idx] = kval;
  v[idx] = vval;
}

// ---------------------------------------------------------------------------
// Fused attention: one wave per (b,h,i) query row. Scores in LDS, online
// softmax (max->exp->sum), then PV with lane=dim. Bias/causal for self-attn.
// out layout: (B, N, H*DH)
// ---------------------------------------------------------------------------
__global__ __launch_bounds__(64) void attn_kernel(const float* __restrict__ q,
                                                  const float* __restrict__ kbuf,
                                                  const float* __restrict__ vbuf,
                                                  const float* __restrict__ rel_emb,
                                                  float* __restrict__ out,
                                                  int n_keys, int causal, int use_bias) {
  __shared__ float qs[64];
  __shared__ float sc[1025];
  int bid = blockIdx.x;              // (b*8+h)*1024 + i
  int lane = threadIdx.x;
  int i = bid & 1023;
  int h = (bid >> 10) & 7;
  int b = bid >> 13;

  qs[lane] = q[(size_t)bid * 64 + lane];
  __syncthreads();

  int valid = causal ? (i + 2) : n_keys;
  const float* kb = kbuf + (size_t)b * n_keys * 64;

  float lmax = -INFINITY;
  for (int j = lane; j < valid; j += 64) {
    const float4* kr = (const float4*)(kb + (size_t)j * 64);
    const float4* q4 = (const float4*)qs;
    float dot = 0.f;
    #pragma unroll
    for (int t = 0; t < 16; t++) {
      float4 kk = kr[t], qq = q4[t];
      dot += kk.x * qq.x + kk.y * qq.y + kk.z * qq.z + kk.w * qq.w;
    }
    if (use_bias) {
      int nd = i - j; if (nd < 0) nd = 0;
      int bucket;
      if (nd < 16) bucket = nd;
      else {
        bucket = 16 + (int)(logf((float)nd * (1.f / 16.f)) * (16.f / logf(8.f)));
        if (bucket > 31) bucket = 31;
      }
      dot += rel_emb[bucket * HH + h];
    }
    sc[j] = dot;
    lmax = fmaxf(lmax, dot);
  }
  #pragma unroll
  for (int o = 32; o > 0; o >>= 1) lmax = fmaxf(lmax, __shfl_xor(lmax, o));

  float lsum = 0.f;
  for (int j = lane; j < valid; j += 64) {
    float p = expf(sc[j] - lmax);
    sc[j] = p;
    lsum += p;
  }
  #pragma unroll
  for (int o = 32; o > 0; o >>= 1) lsum += __shfl_xor(lsum, o);
  __syncthreads();

  float inv_sum = 1.f / lsum;
  const float* vb = vbuf + (size_t)b * n_keys * 64 + lane;
  float acc = 0.f;
  int j = 0;
  for (; j + 4 <= valid; j += 4) {
    acc += sc[j]     * vb[(size_t)j * 64];
    acc += sc[j + 1] * vb[(size_t)(j + 1) * 64];
    acc += sc[j + 2] * vb[(size_t)(j + 2) * 64];
    acc += sc[j + 3] * vb[(size_t)(j + 3) * 64];
  }
  for (; j < valid; j++) acc += sc[j] * vb[(size_t)j * 64];

  out[((size_t)(b * NN + i)) * DD + h * DHH + lane] = acc * inv_sum;
}

// ---------------------------------------------------------------------------
// Orchestration
// ---------------------------------------------------------------------------
extern "C" void kernel_launch(void* const* d_in, const int* in_sizes, int n_in,
                              void* d_out, int out_size, void* d_ws, size_t ws_size,
                              hipStream_t stream) {
  const float* in_x      = (const float*)d_in[0];
  const float* in_ctx    = (const float*)d_in[1];
  const float* rel_emb   = (const float*)d_in[2];
  const float* sa_norm_g = (const float*)d_in[3];
  const float* sa_wq     = (const float*)d_in[4];
  const float* sa_wkv    = (const float*)d_in[5];
  const float* sa_nullkv = (const float*)d_in[6];
  const float* sa_wo     = (const float*)d_in[7];
  const float* sa_out_g  = (const float*)d_in[8];
  const float* ca_norm_g = (const float*)d_in[9];
  const float* ca_ctx_g  = (const float*)d_in[10];
  const float* ca_wq     = (const float*)d_in[11];
  const float* ca_wkv    = (const float*)d_in[12];
  const float* ca_nullkv = (const float*)d_in[13];
  const float* ca_wo     = (const float*)d_in[14];
  const float* ca_out_g  = (const float*)d_in[15];
  const float* ff_norm_g = (const float*)d_in[16];
  const float* ff_w1     = (const float*)d_in[17];
  const float* ff_w2     = (const float*)d_in[18];
  const float* norm_g    = (const float*)d_in[19];

  const size_t XSZ = (size_t)BB * NN * DD;   // 2,097,152

  float* x_cur = (float*)d_out;              // residual stream lives in d_out
  float* w = (float*)d_ws;
  float* xn    = w;                          // 2,097,152
  float* qlin  = w + XSZ;                    // also proj buffer
  float* qbuf  = w + 2 * XSZ;                // (B,H,N,DH)
  float* big   = w + 3 * XSZ;                // attn_out (2.1M) / gated (8.39M)
  float* kvlin = big + (size_t)BB * NN * FFI / 1;   // big is 8,388,608 floats
  // careful: big region size = B*N*FI = 8,388,608 floats
  kvlin = big + 8388608;                     // 524,288
  float* kbuf  = kvlin + 524288;             // 262,400
  float* vbuf  = kbuf + 262400;              // 262,400
  float* ctxn  = vbuf + 262400;              // 524,288

  hipMemcpyAsync(x_cur, in_x, sizeof(float) * XSZ, hipMemcpyDeviceToDevice, stream);

  dim3 b256(256), b64(64);
  const int ROWS = BB * NN;                  // 4096

  for (int l = 0; l < LL; l++) {
    const float* l_sa_norm = sa_norm_g + l * DD;
    const float* l_sa_wq   = sa_wq   + (size_t)l * DD * DD;
    const float* l_sa_wkv  = sa_wkv  + (size_t)l * DD * 128;
    const float* l_sa_null = sa_nullkv + l * 2 * DHH;
    const float* l_sa_wo   = sa_wo   + (size_t)l * DD * DD;
    const float* l_sa_outg = sa_out_g + l * DD;
    const float* l_ca_norm = ca_norm_g + l * DD;
    const float* l_ca_ctxg = ca_ctx_g + l * PP;
    const float* l_ca_wq   = ca_wq   + (size_t)l * DD * DD;
    const float* l_ca_wkv  = ca_wkv  + (size_t)l * PP * 128;
    const float* l_ca_null = ca_nullkv + l * 2 * DHH;
    const float* l_ca_wo   = ca_wo   + (size_t)l * DD * DD;
    const float* l_ca_outg = ca_out_g + l * DD;
    const float* l_ff_norm = ff_norm_g + l * DD;
    const float* l_ff_w1   = ff_w1   + (size_t)l * DD * 2 * FFI;
    const float* l_ff_w2   = ff_w2   + (size_t)l * FFI * DD;

    // ---- self attention ----
    ln_kernel<<<ROWS, b256, 0, stream>>>(x_cur, l_sa_norm, nullptr, xn, DD, 0);
    gemm_kernel<<<dim3(8, 64), b256, 0, stream>>>(xn, l_sa_wq, qlin, nullptr, 4096, 512, 512);
    qprep_kernel<<<8192, b256, 0, stream>>>(qlin, qbuf, 1);
    gemm_kernel<<<dim3(2, 64), b256, 0, stream>>>(xn, l_sa_wkv, kvlin, nullptr, 4096, 128, 512);
    kvprep_kernel<<<1025, b256, 0, stream>>>(kvlin, l_sa_null, kbuf, vbuf, 1025, 1024, 1);
    attn_kernel<<<32768, b64, 0, stream>>>(qbuf, kbuf, vbuf, rel_emb, big, 1025, 1, 1);
    gemm_kernel<<<dim3(8, 64), b256, 0, stream>>>(big, l_sa_wo, qlin, nullptr, 4096, 512, 512);
    ln_kernel<<<ROWS, b256, 0, stream>>>(qlin, l_sa_outg, x_cur, x_cur, DD, 0);

    // ---- cross attention ----
    ln_kernel<<<ROWS, b256, 0, stream>>>(x_cur, l_ca_norm, nullptr, xn, DD, 0);
    ln_kernel<<<BB * MM, b256, 0, stream>>>(in_ctx, l_ca_ctxg, nullptr, ctxn, PP, 0);
    gemm_kernel<<<dim3(8, 64), b256, 0, stream>>>(xn, l_ca_wq, qlin, nullptr, 4096, 512, 512);
    qprep_kernel<<<8192, b256, 0, stream>>>(qlin, qbuf, 0);
    gemm_kernel<<<dim3(2, 32), b256, 0, stream>>>(ctxn, l_ca_wkv, kvlin, nullptr, 2048, 128, 256);
    kvprep_kernel<<<513, b256, 0, stream>>>(kvlin, l_ca_null, kbuf, vbuf, 513, 512, 0);
    attn_kernel<<<32768, b64, 0, stream>>>(qbuf, kbuf, vbuf, nullptr, big, 513, 0, 0);
    gemm_kernel<<<dim3(8, 64), b256, 0, stream>>>(big, l_ca_wo, qlin, nullptr, 4096, 512, 512);
    ln_kernel<<<ROWS, b256, 0, stream>>>(qlin, l_ca_outg, x_cur, x_cur, DD, 0);

    // ---- feed forward ----
    ln_kernel<<<ROWS, b256, 0, stream>>>(x_cur, l_ff_norm, nullptr, xn, DD, 0);
    gemm_gated_kernel<<<dim3(32, 64), b256, 0, stream>>>(xn, l_ff_w1, big, 4096, 2048, 512);
    gemm_kernel<<<dim3(8, 64), b256, 0, stream>>>(big, l_ff_w2, x_cur, x_cur, 4096, 512, 2048);
  }

  // final stable layernorm, in-place into d_out
  ln_kernel<<<ROWS, b256, 0, stream>>>(x_cur, norm_g, nullptr, x_cur, DD, 1);
}

// Round 2
// 7578.661 us; speedup vs baseline: 1.8101x; 1.8101x over previous
//
#include <hip/hip_runtime.h>
#include <hip/hip_bf16.h>
#include <math.h>

// Problem constants
#define BB 4
#define NN 1024
#define MM 512
#define DD 512
#define PP 256
#define HH 8
#define DHH 64
#define LL 6
#define FFI 2048

// ---------------------------------------------------------------------------
// LayerNorm: y[row] = LN(x[row]) * g (+ resid[row]); stable => x /= max(x) first
// ---------------------------------------------------------------------------
__global__ __launch_bounds__(256) void ln_kernel(const float* __restrict__ x,
                                                 const float* __restrict__ g,
                                                 const float* __restrict__ resid,
                                                 float* __restrict__ y,
                                                 int cols, int stable) {
  __shared__ float sbuf[8];
  int row = blockIdx.x;
  const float* xr = x + (size_t)row * cols;
  int tid = threadIdx.x;

  float inv_mx = 1.f;
  if (stable) {
    float mx = -INFINITY;
    for (int c = tid; c < cols; c += 256) mx = fmaxf(mx, xr[c]);
    #pragma unroll
    for (int o = 32; o > 0; o >>= 1) mx = fmaxf(mx, __shfl_xor(mx, o));
    if ((tid & 63) == 0) sbuf[tid >> 6] = mx;
    __syncthreads();
    mx = fmaxf(fmaxf(sbuf[0], sbuf[1]), fmaxf(sbuf[2], sbuf[3]));
    __syncthreads();
    inv_mx = 1.f / mx;
  }

  float sum = 0.f, ss = 0.f;
  for (int c = tid; c < cols; c += 256) {
    float v = xr[c] * inv_mx;
    sum += v; ss += v * v;
  }
  #pragma unroll
  for (int o = 32; o > 0; o >>= 1) { sum += __shfl_xor(sum, o); ss += __shfl_xor(ss, o); }
  if ((tid & 63) == 0) { sbuf[tid >> 6] = sum; sbuf[4 + (tid >> 6)] = ss; }
  __syncthreads();
  sum = sbuf[0] + sbuf[1] + sbuf[2] + sbuf[3];
  ss  = sbuf[4] + sbuf[5] + sbuf[6] + sbuf[7];

  float mean = sum / cols;
  float var  = ss / cols - mean * mean;
  float r = rsqrtf(var + 1e-5f);
  for (int c = tid; c < cols; c += 256) {
    float v = (xr[c] * inv_mx - mean) * r * g[c];
    if (resid) v += resid[(size_t)row * cols + c];
    y[(size_t)row * cols + c] = v;
  }
}

// ---------------------------------------------------------------------------
// fp32 tiled GEMM: C(MxN) = A(MxK) @ B(KxN) [+ res]; all dims %64==0 (K%16)
// ---------------------------------------------------------------------------
#define GTM 64
#define GTN 64
#define GTK 16
__global__ __launch_bounds__(256) void gemm_kernel(const float* __restrict__ A,
                                                   const float* __restrict__ B,
                                                   float* __restrict__ C,
                                                   const float* __restrict__ res,
                                                   int M, int N, int K) {
  __shared__ float As[GTK][GTM + 1];
  __shared__ float Bs[GTK][GTN];
  int tid = threadIdx.x;
  int bm = blockIdx.y * GTM, bn = blockIdx.x * GTN;
  int tx = tid & 15, ty = tid >> 4;
  float acc[4][4] = {};

  for (int k0 = 0; k0 < K; k0 += GTK) {
    #pragma unroll
    for (int i = 0; i < 4; i++) {
      int idx = tid + i * 256;
      int m = idx >> 4, kk = idx & 15;
      As[kk][m] = A[(size_t)(bm + m) * K + k0 + kk];
    }
    #pragma unroll
    for (int i = 0; i < 4; i++) {
      int idx = tid + i * 256;
      int kk2 = idx >> 6, n = idx & 63;
      Bs[kk2][n] = B[(size_t)(k0 + kk2) * N + bn + n];
    }
    __syncthreads();
    #pragma unroll
    for (int kk = 0; kk < GTK; kk++) {
      float a[4], b[4];
      #pragma unroll
      for (int i = 0; i < 4; i++) a[i] = As[kk][ty * 4 + i];
      #pragma unroll
      for (int j = 0; j < 4; j++) b[j] = Bs[kk][tx * 4 + j];
      #pragma unroll
      for (int i = 0; i < 4; i++)
        #pragma unroll
        for (int j = 0; j < 4; j++) acc[i][j] += a[i] * b[j];
    }
    __syncthreads();
  }

  #pragma unroll
  for (int i = 0; i < 4; i++) {
    int m = bm + ty * 4 + i;
    #pragma unroll
    for (int j = 0; j < 4; j++) {
      int n = bn + tx * 4 + j;
      float v = acc[i][j];
      if (res) v += res[(size_t)m * N + n];
      C[(size_t)m * N + n] = v;
    }
  }
}

// ---------------------------------------------------------------------------
// Gated FF GEMM: W is K x 2*FI. C[m][n] = h * silu(gate)
// ---------------------------------------------------------------------------
__global__ __launch_bounds__(256) void gemm_gated_kernel(const float* __restrict__ A,
                                                         const float* __restrict__ B,
                                                         float* __restrict__ C,
                                                         int M, int FIc, int K) {
  __shared__ float As[GTK][GTM + 1];
  __shared__ float Bs1[GTK][GTN];
  __shared__ float Bs2[GTK][GTN];
  int tid = threadIdx.x;
  int bm = blockIdx.y * GTM, bn = blockIdx.x * GTN;
  int tx = tid & 15, ty = tid >> 4;
  int ldb = 2 * FIc;
  float acc1[4][4] = {};
  float acc2[4][4] = {};

  for (int k0 = 0; k0 < K; k0 += GTK) {
    #pragma unroll
    for (int i = 0; i < 4; i++) {
      int idx = tid + i * 256;
      int m = idx >> 4, kk = idx & 15;
      As[kk][m] = A[(size_t)(bm + m) * K + k0 + kk];
    }
    #pragma unroll
    for (int i = 0; i < 4; i++) {
      int idx = tid + i * 256;
      int kk2 = idx >> 6, n = idx & 63;
      Bs1[kk2][n] = B[(size_t)(k0 + kk2) * ldb + bn + n];
      Bs2[kk2][n] = B[(size_t)(k0 + kk2) * ldb + FIc + bn + n];
    }
    __syncthreads();
    #pragma unroll
    for (int kk = 0; kk < GTK; kk++) {
      float a[4], b1[4], b2[4];
      #pragma unroll
      for (int i = 0; i < 4; i++) a[i] = As[kk][ty * 4 + i];
      #pragma unroll
      for (int j = 0; j < 4; j++) { b1[j] = Bs1[kk][tx * 4 + j]; b2[j] = Bs2[kk][tx * 4 + j]; }
      #pragma unroll
      for (int i = 0; i < 4; i++)
        #pragma unroll
        for (int j = 0; j < 4; j++) { acc1[i][j] += a[i] * b1[j]; acc2[i][j] += a[i] * b2[j]; }
    }
    __syncthreads();
  }

  #pragma unroll
  for (int i = 0; i < 4; i++) {
    int m = bm + ty * 4 + i;
    #pragma unroll
    for (int j = 0; j < 4; j++) {
      int n = bn + tx * 4 + j;
      float h = acc1[i][j], gt = acc2[i][j];
      float sg = 1.f / (1.f + expf(-gt));
      C[(size_t)m * FIc + n] = h * gt * sg;
    }
  }
}

// ---------------------------------------------------------------------------
// Q prep: q[b][h][i][d] = rotary?(q_lin[b][i][h*64+d] * 0.125)
// ---------------------------------------------------------------------------
__global__ __launch_bounds__(256) void qprep_kernel(const float* __restrict__ q_lin,
                                                    float* __restrict__ q, int use_rot) {
  int idx = blockIdx.x * 256 + threadIdx.x;   // ((b*8+h)*1024+i)*64+d
  int d = idx & 63;
  int i = (idx >> 6) & 1023;
  int h = (idx >> 16) & 7;
  int b = idx >> 19;
  const float* src = q_lin + ((size_t)(b * NN + i)) * DD + h * DHH;
  float val = src[d] * 0.125f;
  if (use_rot && d < 32) {
    int dd = d & 15;
    float inv = powf(10000.f, -(float)dd * (1.f / 16.f));
    float a = (float)i * inv;
    float other = src[(d < 16) ? d + 16 : d - 16] * 0.125f;
    val = val * cosf(a) + ((d < 16) ? -other : other) * sinf(a);
  }
  q[idx] = val;
}

// ---------------------------------------------------------------------------
// KV prep: prepend null kv at j=0; rotary on k (self-attn only).
// ---------------------------------------------------------------------------
__global__ __launch_bounds__(256) void kvprep_kernel(const float* __restrict__ kv_lin,
                                                     const float* __restrict__ null_kv,
                                                     float* __restrict__ k, float* __restrict__ v,
                                                     int NK, int NT, int use_rot) {
  int idx = blockIdx.x * 256 + threadIdx.x;
  int d = idx & 63;
  int j = (idx >> 6) % NK;
  int b = idx / (NK * 64);
  float kval, vval;
  if (j == 0) {
    kval = null_kv[d];
    vval = null_kv[64 + d];
  } else {
    int t = j - 1;
    const float* src = kv_lin + ((size_t)(b * NT + t)) * 128;
    kval = src[d];
    vval = src[64 + d];
    if (use_rot && d < 32) {
      int dd = d & 15;
      float inv = powf(10000.f, -(float)dd * (1.f / 16.f));
      float a = (float)t * inv;
      float other = src[(d < 16) ? d + 16 : d - 16];
      kval = kval * cosf(a) + ((d < 16) ? -other : other) * sinf(a);
    }
  }
  k[idx] = kval;
  v[idx] = vval;
}

// ---------------------------------------------------------------------------
// Tiled flash-style attention.
// Block = 256 threads; handles TQ=32 query rows of one (b,h); iterates 64-key
// tiles: K^T,V staged in LDS (shared by all 32 rows), online softmax.
// q: (B,H,N,64) pre-scaled+rotary; k/v: (B,NK,64); out: (B,N,512).
// ---------------------------------------------------------------------------
#define TQ 32
#define TK 64
#define QT_S 36   // Qt[d][r]  stride (36%4==0 for b128-aligned float4 over r)
#define KT_S 66   // Kt[d][j], Vs[j][d] stride (even for b64 alignment)
#define ST_S 36   // St[j][r]  stride

__global__ __launch_bounds__(256) void attn_tile_kernel(
    const float* __restrict__ q,
    const float* __restrict__ kbuf,
    const float* __restrict__ vbuf,
    const float* __restrict__ rel_emb,
    float* __restrict__ out,
    int n_keys, int causal, int use_bias) {
  __shared__ float Qt[64 * QT_S];
  __shared__ float Kt[64 * KT_S];
  __shared__ float Vs[TK * KT_S];
  __shared__ float St[TK * ST_S];
  __shared__ float m_s[TQ], l_s[TQ], al_s[TQ];

  int t = threadIdx.x;
  int bh = blockIdx.y;              // b*8 + h
  int b = bh >> 3, h = bh & 7;
  int i0 = blockIdx.x * TQ;

  // ---- load Q tile transposed: Qt[d][r] ----
  #pragma unroll
  for (int it = 0; it < 2; it++) {
    int fid = t + it * 256;         // 0..511
    int r = fid >> 4, d0 = (fid & 15) * 4;
    const float4 q4 = *(const float4*)(q + (((size_t)bh * NN + i0 + r) << 6) + d0);
    Qt[(d0 + 0) * QT_S + r] = q4.x;
    Qt[(d0 + 1) * QT_S + r] = q4.y;
    Qt[(d0 + 2) * QT_S + r] = q4.z;
    Qt[(d0 + 3) * QT_S + r] = q4.w;
  }
  if (t < TQ) { m_s[t] = -1e30f; l_s[t] = 0.f; }

  // thread layouts
  int rq = (t >> 5) * 4;            // rows r0..r0+3 (phase1 & phase3)
  int j2 = (t & 31) * 2;            // phase1: key pair; phase3: dim pair
  int p2_r = t >> 3;                // phase2: row
  int p2_g = t & 7;                 // phase2: group of 8 keys (interleaved)

  int max_t = causal ? ((i0 + TQ) / TK + 1) : ((n_keys + TK - 1) / TK);

  const float* kb = kbuf + (size_t)b * n_keys * 64;
  const float* vb = vbuf + (size_t)b * n_keys * 64;

  float o[4][2] = {};

  for (int tile = 0; tile < max_t; tile++) {
    int j0 = tile * TK;
    __syncthreads();                // protect Kt/Vs/St from prior-tile readers

    // ---- stage K^T and V for this key tile ----
    #pragma unroll
    for (int it = 0; it < 4; it++) {
      int fid = t + it * 256;       // 0..1023
      int j = fid >> 4, d0 = (fid & 15) * 4;
      int gj = j0 + j;
      float4 k4 = make_float4(0.f, 0.f, 0.f, 0.f);
      float4 v4 = make_float4(0.f, 0.f, 0.f, 0.f);
      if (gj < n_keys) {
        k4 = *(const float4*)(kb + ((size_t)gj << 6) + d0);
        v4 = *(const float4*)(vb + ((size_t)gj << 6) + d0);
      }
      Kt[(d0 + 0) * KT_S + j] = k4.x;
      Kt[(d0 + 1) * KT_S + j] = k4.y;
      Kt[(d0 + 2) * KT_S + j] = k4.z;
      Kt[(d0 + 3) * KT_S + j] = k4.w;
      Vs[j * KT_S + d0 + 0] = v4.x;
      Vs[j * KT_S + d0 + 1] = v4.y;
      Vs[j * KT_S + d0 + 2] = v4.z;
      Vs[j * KT_S + d0 + 3] = v4.w;
    }
    __syncthreads();

    // ---- phase 1: scores S = Q K^T (4 rows x 2 keys per thread) ----
    {
      float s00 = 0, s01 = 0, s10 = 0, s11 = 0, s20 = 0, s21 = 0, s30 = 0, s31 = 0;
      #pragma unroll 4
      for (int d = 0; d < 64; d++) {
        float4 qv = *(const float4*)&Qt[d * QT_S + rq];
        float2 kv = *(const float2*)&Kt[d * KT_S + j2];
        s00 += qv.x * kv.x; s01 += qv.x * kv.y;
        s10 += qv.y * kv.x; s11 += qv.y * kv.y;
        s20 += qv.z * kv.x; s21 += qv.z * kv.y;
        s30 += qv.w * kv.x; s31 += qv.w * kv.y;
      }
      float sv[4][2] = {{s00, s01}, {s10, s11}, {s20, s21}, {s30, s31}};
      #pragma unroll
      for (int rc = 0; rc < 4; rc++) {
        int i = i0 + rq + rc;
        #pragma unroll
        for (int jc = 0; jc < 2; jc++) {
          int gj = j0 + j2 + jc;
          float val = sv[rc][jc];
          if (use_bias) {
            int nd = i - gj; if (nd < 0) nd = 0;
            int bucket;
            if (nd < 16) bucket = nd;
            else {
              bucket = 16 + (int)(__logf((float)nd * (1.f / 16.f)) * (16.f / 2.0794415416798357f));
              if (bucket > 31) bucket = 31;
            }
            val += rel_emb[bucket * HH + h];
          }
          bool ok = (gj < n_keys) && (!causal || gj <= i + 1);
          St[(j2 + jc) * ST_S + rq + rc] = ok ? val : -1e30f;
        }
      }
    }
    __syncthreads();

    // ---- phase 2: online softmax (row p2_r, keys p2_g + u*8) ----
    {
      float vals[8];
      float mx = -1e30f;
      #pragma unroll
      for (int u = 0; u < 8; u++) {
        vals[u] = St[(u * 8 + p2_g) * ST_S + p2_r];
        mx = fmaxf(mx, vals[u]);
      }
      mx = fmaxf(mx, __shfl_xor(mx, 1));
      mx = fmaxf(mx, __shfl_xor(mx, 2));
      mx = fmaxf(mx, __shfl_xor(mx, 4));
      float m_old = m_s[p2_r];
      float m_new = fmaxf(m_old, mx);
      float sum = 0.f;
      #pragma unroll
      for (int u = 0; u < 8; u++) {
        float p = __expf(vals[u] - m_new);
        St[(u * 8 + p2_g) * ST_S + p2_r] = p;
        sum += p;
      }
      sum += __shfl_xor(sum, 1);
      sum += __shfl_xor(sum, 2);
      sum += __shfl_xor(sum, 4);
      if (p2_g == 0) {
        float alpha = __expf(m_old - m_new);
        al_s[p2_r] = alpha;
        m_s[p2_r] = m_new;
        l_s[p2_r] = l_s[p2_r] * alpha + sum;
      }
    }
    __syncthreads();

    // ---- phase 3: O = O*alpha + P V (4 rows x 2 dims per thread) ----
    {
      float a0 = al_s[rq + 0], a1 = al_s[rq + 1], a2 = al_s[rq + 2], a3 = al_s[rq + 3];
      o[0][0] *= a0; o[0][1] *= a0;
      o[1][0] *= a1; o[1][1] *= a1;
      o[2][0] *= a2; o[2][1] *= a2;
      o[3][0] *= a3; o[3][1] *= a3;
      #pragma unroll 4
      for (int j = 0; j < TK; j++) {
        float4 pv = *(const float4*)&St[j * ST_S + rq];
        float2 vv = *(const float2*)&Vs[j * KT_S + j2];
        o[0][0] += pv.x * vv.x; o[0][1] += pv.x * vv.y;
        o[1][0] += pv.y * vv.x; o[1][1] += pv.y * vv.y;
        o[2][0] += pv.z * vv.x; o[2][1] += pv.z * vv.y;
        o[3][0] += pv.w * vv.x; o[3][1] += pv.w * vv.y;
      }
    }
  }

  // ---- epilogue: normalize, write (B,N,H*64) ----
  #pragma unroll
  for (int rc = 0; rc < 4; rc++) {
    int r = rq + rc;
    float inv = 1.f / l_s[r];
    float2 res = make_float2(o[rc][0] * inv, o[rc][1] * inv);
    *(float2*)(out + ((size_t)(b * NN + i0 + r)) * DD + h * 64 + j2) = res;
  }
}

// ---------------------------------------------------------------------------
// Orchestration
// ---------------------------------------------------------------------------
extern "C" void kernel_launch(void* const* d_in, const int* in_sizes, int n_in,
                              void* d_out, int out_size, void* d_ws, size_t ws_size,
                              hipStream_t stream) {
  const float* in_x      = (const float*)d_in[0];
  const float* in_ctx    = (const float*)d_in[1];
  const float* rel_emb   = (const float*)d_in[2];
  const float* sa_norm_g = (const float*)d_in[3];
  const float* sa_wq     = (const float*)d_in[4];
  const float* sa_wkv    = (const float*)d_in[5];
  const float* sa_nullkv = (const float*)d_in[6];
  const float* sa_wo     = (const float*)d_in[7];
  const float* sa_out_g  = (const float*)d_in[8];
  const float* ca_norm_g = (const float*)d_in[9];
  const float* ca_ctx_g  = (const float*)d_in[10];
  const float* ca_wq     = (const float*)d_in[11];
  const float* ca_wkv    = (const float*)d_in[12];
  const float* ca_nullkv = (const float*)d_in[13];
  const float* ca_wo     = (const float*)d_in[14];
  const float* ca_out_g  = (const float*)d_in[15];
  const float* ff_norm_g = (const float*)d_in[16];
  const float* ff_w1     = (const float*)d_in[17];
  const float* ff_w2     = (const float*)d_in[18];
  const float* norm_g    = (const float*)d_in[19];

  const size_t XSZ = (size_t)BB * NN * DD;   // 2,097,152

  float* x_cur = (float*)d_out;              // residual stream lives in d_out
  float* w = (float*)d_ws;
  float* xn    = w;                          // 2,097,152
  float* qlin  = w + XSZ;                    // proj buffer
  float* qbuf  = w + 2 * XSZ;                // (B,H,N,DH)
  float* big   = w + 3 * XSZ;                // attn_out (2.1M) / gated (8.39M)
  float* kvlin = big + 8388608;              // 524,288
  float* kbuf  = kvlin + 524288;             // 262,400
  float* vbuf  = kbuf + 262400;              // 262,400
  float* ctxn  = vbuf + 262400;              // 524,288

  hipMemcpyAsync(x_cur, in_x, sizeof(float) * XSZ, hipMemcpyDeviceToDevice, stream);

  dim3 b256(256);
  const int ROWS = BB * NN;                  // 4096
  dim3 attn_grid(NN / TQ, BB * HH);          // (32, 32)

  for (int l = 0; l < LL; l++) {
    const float* l_sa_norm = sa_norm_g + l * DD;
    const float* l_sa_wq   = sa_wq   + (size_t)l * DD * DD;
    const float* l_sa_wkv  = sa_wkv  + (size_t)l * DD * 128;
    const float* l_sa_null = sa_nullkv + l * 2 * DHH;
    const float* l_sa_wo   = sa_wo   + (size_t)l * DD * DD;
    const float* l_sa_outg = sa_out_g + l * DD;
    const float* l_ca_norm = ca_norm_g + l * DD;
    const float* l_ca_ctxg = ca_ctx_g + l * PP;
    const float* l_ca_wq   = ca_wq   + (size_t)l * DD * DD;
    const float* l_ca_wkv  = ca_wkv  + (size_t)l * PP * 128;
    const float* l_ca_null = ca_nullkv + l * 2 * DHH;
    const float* l_ca_wo   = ca_wo   + (size_t)l * DD * DD;
    const float* l_ca_outg = ca_out_g + l * DD;
    const float* l_ff_norm = ff_norm_g + l * DD;
    const float* l_ff_w1   = ff_w1   + (size_t)l * DD * 2 * FFI;
    const float* l_ff_w2   = ff_w2   + (size_t)l * FFI * DD;

    // ---- self attention ----
    ln_kernel<<<ROWS, b256, 0, stream>>>(x_cur, l_sa_norm, nullptr, xn, DD, 0);
    gemm_kernel<<<dim3(8, 64), b256, 0, stream>>>(xn, l_sa_wq, qlin, nullptr, 4096, 512, 512);
    qprep_kernel<<<8192, b256, 0, stream>>>(qlin, qbuf, 1);
    gemm_kernel<<<dim3(2, 64), b256, 0, stream>>>(xn, l_sa_wkv, kvlin, nullptr, 4096, 128, 512);
    kvprep_kernel<<<1025, b256, 0, stream>>>(kvlin, l_sa_null, kbuf, vbuf, 1025, 1024, 1);
    attn_tile_kernel<<<attn_grid, b256, 0, stream>>>(qbuf, kbuf, vbuf, rel_emb, big, 1025, 1, 1);
    gemm_kernel<<<dim3(8, 64), b256, 0, stream>>>(big, l_sa_wo, qlin, nullptr, 4096, 512, 512);
    ln_kernel<<<ROWS, b256, 0, stream>>>(qlin, l_sa_outg, x_cur, x_cur, DD, 0);

    // ---- cross attention ----
    ln_kernel<<<ROWS, b256, 0, stream>>>(x_cur, l_ca_norm, nullptr, xn, DD, 0);
    ln_kernel<<<BB * MM, b256, 0, stream>>>(in_ctx, l_ca_ctxg, nullptr, ctxn, PP, 0);
    gemm_kernel<<<dim3(8, 64), b256, 0, stream>>>(xn, l_ca_wq, qlin, nullptr, 4096, 512, 512);
    qprep_kernel<<<8192, b256, 0, stream>>>(qlin, qbuf, 0);
    gemm_kernel<<<dim3(2, 32), b256, 0, stream>>>(ctxn, l_ca_wkv, kvlin, nullptr, 2048, 128, 256);
    kvprep_kernel<<<513, b256, 0, stream>>>(kvlin, l_ca_null, kbuf, vbuf, 513, 512, 0);
    attn_tile_kernel<<<attn_grid, b256, 0, stream>>>(qbuf, kbuf, vbuf, nullptr, big, 513, 0, 0);
    gemm_kernel<<<dim3(8, 64), b256, 0, stream>>>(big, l_ca_wo, qlin, nullptr, 4096, 512, 512);
    ln_kernel<<<ROWS, b256, 0, stream>>>(qlin, l_ca_outg, x_cur, x_cur, DD, 0);

    // ---- feed forward ----
    ln_kernel<<<ROWS, b256, 0, stream>>>(x_cur, l_ff_norm, nullptr, xn, DD, 0);
    gemm_gated_kernel<<<dim3(32, 64), b256, 0, stream>>>(xn, l_ff_w1, big, 4096, 2048, 512);
    gemm_kernel<<<dim3(8, 64), b256, 0, stream>>>(big, l_ff_w2, x_cur, x_cur, 4096, 512, 2048);
  }

  // final stable layernorm, in-place into d_out
  ln_kernel<<<ROWS, b256, 0, stream>>>(x_cur, norm_g, nullptr, x_cur, DD, 1);
}

// Round 3
// 3594.015 us; speedup vs baseline: 3.8169x; 2.1087x over previous
//
#include <hip/hip_runtime.h>
#include <hip/hip_bf16.h>
#include <math.h>

// Problem constants
#define BB 4
#define NN 1024
#define MM 512
#define DD 512
#define PP 256
#define HH 8
#define DHH 64
#define LL 6
#define FFI 2048

typedef unsigned short u16;
typedef __attribute__((ext_vector_type(8))) short frag8;   // 8 bf16 (4 VGPRs)
typedef __attribute__((ext_vector_type(4))) float f32x4;   // MFMA C/D

__device__ __forceinline__ u16 f2bf(float f) {
  union { float f; unsigned u; } x; x.f = f;
  unsigned u = x.u;
  return (u16)((u + 0x7FFFu + ((u >> 16) & 1u)) >> 16);
}

// ---------------------------------------------------------------------------
// LayerNorm: y[row] = LN(x[row]) * g (+ resid[row]); obf => write bf16
// ---------------------------------------------------------------------------
__global__ __launch_bounds__(256) void ln_kernel(const float* __restrict__ x,
                                                 const float* __restrict__ g,
                                                 const float* __restrict__ resid,
                                                 void* __restrict__ y,
                                                 int cols, int stable, int obf) {
  __shared__ float sbuf[8];
  int row = blockIdx.x;
  const float* xr = x + (size_t)row * cols;
  int tid = threadIdx.x;

  float inv_mx = 1.f;
  if (stable) {
    float mx = -INFINITY;
    for (int c = tid; c < cols; c += 256) mx = fmaxf(mx, xr[c]);
    #pragma unroll
    for (int o = 32; o > 0; o >>= 1) mx = fmaxf(mx, __shfl_xor(mx, o));
    if ((tid & 63) == 0) sbuf[tid >> 6] = mx;
    __syncthreads();
    mx = fmaxf(fmaxf(sbuf[0], sbuf[1]), fmaxf(sbuf[2], sbuf[3]));
    __syncthreads();
    inv_mx = 1.f / mx;
  }

  float sum = 0.f, ss = 0.f;
  for (int c = tid; c < cols; c += 256) {
    float v = xr[c] * inv_mx;
    sum += v; ss += v * v;
  }
  #pragma unroll
  for (int o = 32; o > 0; o >>= 1) { sum += __shfl_xor(sum, o); ss += __shfl_xor(ss, o); }
  if ((tid & 63) == 0) { sbuf[tid >> 6] = sum; sbuf[4 + (tid >> 6)] = ss; }
  __syncthreads();
  sum = sbuf[0] + sbuf[1] + sbuf[2] + sbuf[3];
  ss  = sbuf[4] + sbuf[5] + sbuf[6] + sbuf[7];

  float mean = sum / cols;
  float var  = ss / cols - mean * mean;
  float r = rsqrtf(var + 1e-5f);
  for (int c = tid; c < cols; c += 256) {
    float v = (xr[c] * inv_mx - mean) * r * g[c];
    if (resid) v += resid[(size_t)row * cols + c];
    if (obf) ((u16*)y)[(size_t)row * cols + c] = f2bf(v);
    else     ((float*)y)[(size_t)row * cols + c] = v;
  }
}

// ---------------------------------------------------------------------------
// Weight convert + transpose: W (K x N fp32, layer stride K*N) -> Wt (N x K bf16)
// grid: (N/32, K/32, nl)
// ---------------------------------------------------------------------------
__global__ __launch_bounds__(256) void wtrans_kernel(const float* __restrict__ W,
                                                     u16* __restrict__ Wt,
                                                     int K, int N) {
  __shared__ float tile[32][33];
  size_t lofs = (size_t)blockIdx.z * K * N;
  const float* Wl = W + lofs;
  u16* Wtl = Wt + lofs;
  int n0 = blockIdx.x * 32, k0 = blockIdx.y * 32;
  int t = threadIdx.x;
  #pragma unroll
  for (int it = 0; it < 4; it++) {
    int idx = t + it * 256;
    int r = idx >> 5, c = idx & 31;
    tile[r][c] = Wl[(size_t)(k0 + r) * N + n0 + c];
  }
  __syncthreads();
  #pragma unroll
  for (int it = 0; it < 4; it++) {
    int idx = t + it * 256;
    int r = idx >> 5, c = idx & 31;
    Wtl[(size_t)(n0 + r) * K + k0 + c] = f2bf(tile[c][r]);
  }
}

// ---------------------------------------------------------------------------
// bf16 MFMA GEMM: C(MxN) = A(MxK,bf16) @ Bt(NxK,bf16)^T  [+ res fp32]
// 256 threads = 4 waves in 2x2; tile TM x TN, BK=32.
// LDS rows padded to 40 ushorts (80 B) -> conflict-free b128 frag reads.
// ---------------------------------------------------------------------------
#define LSTR 40

template<int TM, int TN, int RES>
__global__ __launch_bounds__(256) void mfma_gemm(const u16* __restrict__ A,
                                                 const u16* __restrict__ Bt,
                                                 float* __restrict__ C,
                                                 const float* __restrict__ res,
                                                 int M, int N, int K) {
  constexpr int TM2 = TM / 2, TN2 = TN / 2;
  constexpr int IT = TM2 / 16, JT = TN2 / 16;
  constexpr int ASLOT = TM * 4 / 256, BSLOT = TN * 4 / 256;
  __shared__ u16 As[TM * LSTR];
  __shared__ u16 Bs[TN * LSTR];
  int t = threadIdx.x;
  int w = t >> 6, lane = t & 63;
  int bm = blockIdx.y * TM, bn = blockIdx.x * TN;
  int wr = (w >> 1) * TM2, wc = (w & 1) * TN2;
  int lm = lane & 15, q = lane >> 4;

  f32x4 acc[IT][JT] = {};

  for (int k0 = 0; k0 < K; k0 += 32) {
    __syncthreads();
    #pragma unroll
    for (int i = 0; i < ASLOT; i++) {
      int s = t + i * 256; int m = s >> 2, c = s & 3;
      uint4 d = *(const uint4*)(A + (size_t)(bm + m) * K + k0 + c * 8);
      *(uint4*)&As[m * LSTR + c * 8] = d;
    }
    #pragma unroll
    for (int i = 0; i < BSLOT; i++) {
      int s = t + i * 256; int n = s >> 2, c = s & 3;
      uint4 d = *(const uint4*)(Bt + (size_t)(bn + n) * K + k0 + c * 8);
      *(uint4*)&Bs[n * LSTR + c * 8] = d;
    }
    __syncthreads();
    frag8 a[IT], b[JT];
    #pragma unroll
    for (int i = 0; i < IT; i++) a[i] = *(const frag8*)&As[(wr + i * 16 + lm) * LSTR + q * 8];
    #pragma unroll
    for (int j = 0; j < JT; j++) b[j] = *(const frag8*)&Bs[(wc + j * 16 + lm) * LSTR + q * 8];
    #pragma unroll
    for (int i = 0; i < IT; i++)
      #pragma unroll
      for (int j = 0; j < JT; j++)
        acc[i][j] = __builtin_amdgcn_mfma_f32_16x16x32_bf16(a[i], b[j], acc[i][j], 0, 0, 0);
  }

  #pragma unroll
  for (int i = 0; i < IT; i++)
    #pragma unroll
    for (int j = 0; j < JT; j++)
      #pragma unroll
      for (int r = 0; r < 4; r++) {
        int row = bm + wr + i * 16 + q * 4 + r;
        int col = bn + wc + j * 16 + lm;
        float v = acc[i][j][r];
        if (RES) v += res[(size_t)row * N + col];
        C[(size_t)row * N + col] = v;
      }
}

// ---------------------------------------------------------------------------
// Gated FF MFMA GEMM: Bt is (2*FI) x K; out C(M x FI, bf16) = h * silu(gate)
// TM=128, TN=64 fixed.
// ---------------------------------------------------------------------------
__global__ __launch_bounds__(256) void mfma_gemm_gated(const u16* __restrict__ A,
                                                       const u16* __restrict__ Bt,
                                                       u16* __restrict__ C,
                                                       int M, int FI, int K) {
  constexpr int TM = 128, TN = 64;
  constexpr int TM2 = 64, TN2 = 32;
  constexpr int IT = 4, JT = 2;
  __shared__ u16 As[TM * LSTR];
  __shared__ u16 Bh[TN * LSTR];
  __shared__ u16 Bg[TN * LSTR];
  int t = threadIdx.x;
  int w = t >> 6, lane = t & 63;
  int bm = blockIdx.y * TM, bn = blockIdx.x * TN;
  int wr = (w >> 1) * TM2, wc = (w & 1) * TN2;
  int lm = lane & 15, q = lane >> 4;

  f32x4 ah[IT][JT] = {};
  f32x4 ag[IT][JT] = {};

  for (int k0 = 0; k0 < K; k0 += 32) {
    __syncthreads();
    #pragma unroll
    for (int i = 0; i < 2; i++) {
      int s = t + i * 256; int m = s >> 2, c = s & 3;
      uint4 d = *(const uint4*)(A + (size_t)(bm + m) * K + k0 + c * 8);
      *(uint4*)&As[m * LSTR + c * 8] = d;
    }
    {
      int s = t; int n = s >> 2, c = s & 3;
      uint4 dh = *(const uint4*)(Bt + (size_t)(bn + n) * K + k0 + c * 8);
      uint4 dg = *(const uint4*)(Bt + (size_t)(bn + FI + n) * K + k0 + c * 8);
      *(uint4*)&Bh[n * LSTR + c * 8] = dh;
      *(uint4*)&Bg[n * LSTR + c * 8] = dg;
    }
    __syncthreads();
    frag8 a[IT], bh[JT], bg[JT];
    #pragma unroll
    for (int i = 0; i < IT; i++) a[i] = *(const frag8*)&As[(wr + i * 16 + lm) * LSTR + q * 8];
    #pragma unroll
    for (int j = 0; j < JT; j++) {
      bh[j] = *(const frag8*)&Bh[(wc + j * 16 + lm) * LSTR + q * 8];
      bg[j] = *(const frag8*)&Bg[(wc + j * 16 + lm) * LSTR + q * 8];
    }
    #pragma unroll
    for (int i = 0; i < IT; i++)
      #pragma unroll
      for (int j = 0; j < JT; j++) {
        ah[i][j] = __builtin_amdgcn_mfma_f32_16x16x32_bf16(a[i], bh[j], ah[i][j], 0, 0, 0);
        ag[i][j] = __builtin_amdgcn_mfma_f32_16x16x32_bf16(a[i], bg[j], ag[i][j], 0, 0, 0);
      }
  }

  #pragma unroll
  for (int i = 0; i < IT; i++)
    #pragma unroll
    for (int j = 0; j < JT; j++)
      #pragma unroll
      for (int r = 0; r < 4; r++) {
        int row = bm + wr + i * 16 + q * 4 + r;
        int col = bn + wc + j * 16 + lm;
        float h = ah[i][j][r], g = ag[i][j][r];
        float sg = 1.f / (1.f + __expf(-g));
        C[(size_t)row * FI + col] = f2bf(h * g * sg);
      }
}

// ---------------------------------------------------------------------------
// Q prep: q[b][h][i][d] = rotary?(q_lin[b][i][h*64+d] * 0.125)
// ---------------------------------------------------------------------------
__global__ __launch_bounds__(256) void qprep_kernel(const float* __restrict__ q_lin,
                                                    float* __restrict__ q, int use_rot) {
  int idx = blockIdx.x * 256 + threadIdx.x;   // ((b*8+h)*1024+i)*64+d
  int d = idx & 63;
  int i = (idx >> 6) & 1023;
  int h = (idx >> 16) & 7;
  int b = idx >> 19;
  const float* src = q_lin + ((size_t)(b * NN + i)) * DD + h * DHH;
  float val = src[d] * 0.125f;
  if (use_rot && d < 32) {
    int dd = d & 15;
    float inv = powf(10000.f, -(float)dd * (1.f / 16.f));
    float a = (float)i * inv;
    float other = src[(d < 16) ? d + 16 : d - 16] * 0.125f;
    val = val * cosf(a) + ((d < 16) ? -other : other) * sinf(a);
  }
  q[idx] = val;
}

// ---------------------------------------------------------------------------
// KV prep: prepend null kv at j=0; rotary on k (self-attn only).
// ---------------------------------------------------------------------------
__global__ __launch_bounds__(256) void kvprep_kernel(const float* __restrict__ kv_lin,
                                                     const float* __restrict__ null_kv,
                                                     float* __restrict__ k, float* __restrict__ v,
                                                     int NK, int NT, int use_rot) {
  int idx = blockIdx.x * 256 + threadIdx.x;
  int d = idx & 63;
  int j = (idx >> 6) % NK;
  int b = idx / (NK * 64);
  float kval, vval;
  if (j == 0) {
    kval = null_kv[d];
    vval = null_kv[64 + d];
  } else {
    int t = j - 1;
    const float* src = kv_lin + ((size_t)(b * NT + t)) * 128;
    kval = src[d];
    vval = src[64 + d];
    if (use_rot && d < 32) {
      int dd = d & 15;
      float inv = powf(10000.f, -(float)dd * (1.f / 16.f));
      float a = (float)t * inv;
      float other = src[(d < 16) ? d + 16 : d - 16];
      kval = kval * cosf(a) + ((d < 16) ? -other : other) * sinf(a);
    }
  }
  k[idx] = kval;
  v[idx] = vval;
}

// ---------------------------------------------------------------------------
// Tiled flash-style attention (fp32 math, bf16 output).
// ---------------------------------------------------------------------------
#define TQ 32
#define TK 64
#define QT_S 36
#define KT_S 66
#define ST_S 36

__global__ __launch_bounds__(256) void attn_tile_kernel(
    const float* __restrict__ q,
    const float* __restrict__ kbuf,
    const float* __restrict__ vbuf,
    const float* __restrict__ rel_emb,
    u16* __restrict__ out,
    int n_keys, int causal, int use_bias) {
  __shared__ float Qt[64 * QT_S];
  __shared__ float Kt[64 * KT_S];
  __shared__ float Vs[TK * KT_S];
  __shared__ float St[TK * ST_S];
  __shared__ float m_s[TQ], l_s[TQ], al_s[TQ];

  int t = threadIdx.x;
  int bh = blockIdx.y;              // b*8 + h
  int b = bh >> 3, h = bh & 7;
  int i0 = blockIdx.x * TQ;

  #pragma unroll
  for (int it = 0; it < 2; it++) {
    int fid = t + it * 256;
    int r = fid >> 4, d0 = (fid & 15) * 4;
    const float4 q4 = *(const float4*)(q + (((size_t)bh * NN + i0 + r) << 6) + d0);
    Qt[(d0 + 0) * QT_S + r] = q4.x;
    Qt[(d0 + 1) * QT_S + r] = q4.y;
    Qt[(d0 + 2) * QT_S + r] = q4.z;
    Qt[(d0 + 3) * QT_S + r] = q4.w;
  }
  if (t < TQ) { m_s[t] = -1e30f; l_s[t] = 0.f; }

  int rq = (t >> 5) * 4;
  int j2 = (t & 31) * 2;
  int p2_r = t >> 3;
  int p2_g = t & 7;

  int max_t = causal ? ((i0 + TQ) / TK + 1) : ((n_keys + TK - 1) / TK);

  const float* kb = kbuf + (size_t)b * n_keys * 64;
  const float* vb = vbuf + (size_t)b * n_keys * 64;

  float o[4][2] = {};

  for (int tile = 0; tile < max_t; tile++) {
    int j0 = tile * TK;
    __syncthreads();

    #pragma unroll
    for (int it = 0; it < 4; it++) {
      int fid = t + it * 256;
      int j = fid >> 4, d0 = (fid & 15) * 4;
      int gj = j0 + j;
      float4 k4 = make_float4(0.f, 0.f, 0.f, 0.f);
      float4 v4 = make_float4(0.f, 0.f, 0.f, 0.f);
      if (gj < n_keys) {
        k4 = *(const float4*)(kb + ((size_t)gj << 6) + d0);
        v4 = *(const float4*)(vb + ((size_t)gj << 6) + d0);
      }
      Kt[(d0 + 0) * KT_S + j] = k4.x;
      Kt[(d0 + 1) * KT_S + j] = k4.y;
      Kt[(d0 + 2) * KT_S + j] = k4.z;
      Kt[(d0 + 3) * KT_S + j] = k4.w;
      Vs[j * KT_S + d0 + 0] = v4.x;
      Vs[j * KT_S + d0 + 1] = v4.y;
      Vs[j * KT_S + d0 + 2] = v4.z;
      Vs[j * KT_S + d0 + 3] = v4.w;
    }
    __syncthreads();

    {
      float s00 = 0, s01 = 0, s10 = 0, s11 = 0, s20 = 0, s21 = 0, s30 = 0, s31 = 0;
      #pragma unroll 4
      for (int d = 0; d < 64; d++) {
        float4 qv = *(const float4*)&Qt[d * QT_S + rq];
        float2 kv = *(const float2*)&Kt[d * KT_S + j2];
        s00 += qv.x * kv.x; s01 += qv.x * kv.y;
        s10 += qv.y * kv.x; s11 += qv.y * kv.y;
        s20 += qv.z * kv.x; s21 += qv.z * kv.y;
        s30 += qv.w * kv.x; s31 += qv.w * kv.y;
      }
      float sv[4][2] = {{s00, s01}, {s10, s11}, {s20, s21}, {s30, s31}};
      #pragma unroll
      for (int rc = 0; rc < 4; rc++) {
        int i = i0 + rq + rc;
        #pragma unroll
        for (int jc = 0; jc < 2; jc++) {
          int gj = j0 + j2 + jc;
          float val = sv[rc][jc];
          if (use_bias) {
            int nd = i - gj; if (nd < 0) nd = 0;
            int bucket;
            if (nd < 16) bucket = nd;
            else {
              bucket = 16 + (int)(__logf((float)nd * (1.f / 16.f)) * (16.f / 2.0794415416798357f));
              if (bucket > 31) bucket = 31;
            }
            val += rel_emb[bucket * HH + h];
          }
          bool ok = (gj < n_keys) && (!causal || gj <= i + 1);
          St[(j2 + jc) * ST_S + rq + rc] = ok ? val : -1e30f;
        }
      }
    }
    __syncthreads();

    {
      float vals[8];
      float mx = -1e30f;
      #pragma unroll
      for (int u = 0; u < 8; u++) {
        vals[u] = St[(u * 8 + p2_g) * ST_S + p2_r];
        mx = fmaxf(mx, vals[u]);
      }
      mx = fmaxf(mx, __shfl_xor(mx, 1));
      mx = fmaxf(mx, __shfl_xor(mx, 2));
      mx = fmaxf(mx, __shfl_xor(mx, 4));
      float m_old = m_s[p2_r];
      float m_new = fmaxf(m_old, mx);
      float sum = 0.f;
      #pragma unroll
      for (int u = 0; u < 8; u++) {
        float p = __expf(vals[u] - m_new);
        St[(u * 8 + p2_g) * ST_S + p2_r] = p;
        sum += p;
      }
      sum += __shfl_xor(sum, 1);
      sum += __shfl_xor(sum, 2);
      sum += __shfl_xor(sum, 4);
      if (p2_g == 0) {
        float alpha = __expf(m_old - m_new);
        al_s[p2_r] = alpha;
        m_s[p2_r] = m_new;
        l_s[p2_r] = l_s[p2_r] * alpha + sum;
      }
    }
    __syncthreads();

    {
      float a0 = al_s[rq + 0], a1 = al_s[rq + 1], a2 = al_s[rq + 2], a3 = al_s[rq + 3];
      o[0][0] *= a0; o[0][1] *= a0;
      o[1][0] *= a1; o[1][1] *= a1;
      o[2][0] *= a2; o[2][1] *= a2;
      o[3][0] *= a3; o[3][1] *= a3;
      #pragma unroll 4
      for (int j = 0; j < TK; j++) {
        float4 pv = *(const float4*)&St[j * ST_S + rq];
        float2 vv = *(const float2*)&Vs[j * KT_S + j2];
        o[0][0] += pv.x * vv.x; o[0][1] += pv.x * vv.y;
        o[1][0] += pv.y * vv.x; o[1][1] += pv.y * vv.y;
        o[2][0] += pv.z * vv.x; o[2][1] += pv.z * vv.y;
        o[3][0] += pv.w * vv.x; o[3][1] += pv.w * vv.y;
      }
    }
  }

  #pragma unroll
  for (int rc = 0; rc < 4; rc++) {
    int r = rq + rc;
    float inv = 1.f / l_s[r];
    unsigned pack = (unsigned)f2bf(o[rc][0] * inv) | ((unsigned)f2bf(o[rc][1] * inv) << 16);
    *(unsigned*)(out + ((size_t)(b * NN + i0 + r)) * DD + h * 64 + j2) = pack;
  }
}

// ---------------------------------------------------------------------------
// Orchestration
// ---------------------------------------------------------------------------
extern "C" void kernel_launch(void* const* d_in, const int* in_sizes, int n_in,
                              void* d_out, int out_size, void* d_ws, size_t ws_size,
                              hipStream_t stream) {
  const float* in_x      = (const float*)d_in[0];
  const float* in_ctx    = (const float*)d_in[1];
  const float* rel_emb   = (const float*)d_in[2];
  const float* sa_norm_g = (const float*)d_in[3];
  const float* sa_wq     = (const float*)d_in[4];
  const float* sa_wkv    = (const float*)d_in[5];
  const float* sa_nullkv = (const float*)d_in[6];
  const float* sa_wo     = (const float*)d_in[7];
  const float* sa_out_g  = (const float*)d_in[8];
  const float* ca_norm_g = (const float*)d_in[9];
  const float* ca_ctx_g  = (const float*)d_in[10];
  const float* ca_wq     = (const float*)d_in[11];
  const float* ca_wkv    = (const float*)d_in[12];
  const float* ca_nullkv = (const float*)d_in[13];
  const float* ca_wo     = (const float*)d_in[14];
  const float* ca_out_g  = (const float*)d_in[15];
  const float* ff_norm_g = (const float*)d_in[16];
  const float* ff_w1     = (const float*)d_in[17];
  const float* ff_w2     = (const float*)d_in[18];
  const float* norm_g    = (const float*)d_in[19];

  const size_t XSZ = (size_t)BB * NN * DD;   // 2,097,152

  float* x_cur = (float*)d_out;

  // fp32 scratch
  float* w     = (float*)d_ws;
  float* qlin  = w;                          // 2,097,152
  float* qbuf  = qlin + XSZ;                 // 2,097,152
  float* kvlin = qbuf + XSZ;                 // 524,288
  float* kbuf  = kvlin + 524288;             // 262,400
  float* vbuf  = kbuf + 262400;              // 262,400
  // bf16 scratch
  u16* xn_bf   = (u16*)(vbuf + 262400);      // 2,097,152
  u16* ctxn_bf = xn_bf + XSZ;                // 524,288
  u16* big_bf  = ctxn_bf + 524288;           // 2,097,152 (attn out)
  u16* ffh     = big_bf + XSZ;               // 8,388,608
  u16* wreg    = ffh + 8388608;              // weights bf16 (transposed)

  // per-layer transposed-weight element counts
  const size_t S_WQ = 512 * 512, S_WKV = 512 * 128, S_WO = 512 * 512;
  const size_t S_CWQ = 512 * 512, S_CWKV = 256 * 128, S_CWO = 512 * 512;
  const size_t S_W1 = 512 * 4096, S_W2 = 2048 * 512;
  const size_t S_LAYER = S_WQ + S_WKV + S_WO + S_CWQ + S_CWKV + S_CWO + S_W1 + S_W2;

  // decide mode from ws_size: all-at-once needs base + L*S_LAYER
  const size_t base_elems = (size_t)(wreg - (u16*)d_ws);  // in u16 units (ws viewed as u16)
  const size_t need_all = (base_elems + (size_t)LL * S_LAYER) * 2;
  const int all_mode = (ws_size >= need_all) ? 1 : 0;
  const size_t lstride = all_mode ? S_LAYER : 0;

  dim3 b256(256);

  // weight conversion (all-at-once mode): one pass for all layers
  if (all_mode) {
    u16* p = wreg;
    wtrans_kernel<<<dim3(16, 16, LL), b256, 0, stream>>>(sa_wq,  p, 512, 512);  p += LL * S_WQ;
    wtrans_kernel<<<dim3(4, 16, LL),  b256, 0, stream>>>(sa_wkv, p, 512, 128);  p += LL * S_WKV;
    wtrans_kernel<<<dim3(16, 16, LL), b256, 0, stream>>>(sa_wo,  p, 512, 512);  p += LL * S_WO;
    wtrans_kernel<<<dim3(16, 16, LL), b256, 0, stream>>>(ca_wq,  p, 512, 512);  p += LL * S_CWQ;
    wtrans_kernel<<<dim3(4, 8, LL),   b256, 0, stream>>>(ca_wkv, p, 256, 128);  p += LL * S_CWKV;
    wtrans_kernel<<<dim3(16, 16, LL), b256, 0, stream>>>(ca_wo,  p, 512, 512);  p += LL * S_CWO;
    wtrans_kernel<<<dim3(128, 16, LL),b256, 0, stream>>>(ff_w1,  p, 512, 4096); p += LL * S_W1;
    wtrans_kernel<<<dim3(16, 64, LL), b256, 0, stream>>>(ff_w2,  p, 2048, 512);
  }

  hipMemcpyAsync(x_cur, in_x, sizeof(float) * XSZ, hipMemcpyDeviceToDevice, stream);

  const int ROWS = BB * NN;                  // 4096
  dim3 attn_grid(NN / TQ, BB * HH);          // (32, 32)

  for (int l = 0; l < LL; l++) {
    const float* l_sa_norm = sa_norm_g + l * DD;
    const float* l_sa_null = sa_nullkv + l * 2 * DHH;
    const float* l_sa_outg = sa_out_g + l * DD;
    const float* l_ca_norm = ca_norm_g + l * DD;
    const float* l_ca_ctxg = ca_ctx_g + l * PP;
    const float* l_ca_null = ca_nullkv + l * 2 * DHH;
    const float* l_ca_outg = ca_out_g + l * DD;
    const float* l_ff_norm = ff_norm_g + l * DD;

    // per-layer transposed weight pointers
    u16* base = wreg;
    u16* all_base = wreg;
    u16 *t_wq, *t_wkv, *t_wo, *t_cwq, *t_cwkv, *t_cwo, *t_w1, *t_w2;
    if (all_mode) {
      u16* p = all_base;
      t_wq   = p + l * S_WQ;   p += LL * S_WQ;
      t_wkv  = p + l * S_WKV;  p += LL * S_WKV;
      t_wo   = p + l * S_WO;   p += LL * S_WO;
      t_cwq  = p + l * S_CWQ;  p += LL * S_CWQ;
      t_cwkv = p + l * S_CWKV; p += LL * S_CWKV;
      t_cwo  = p + l * S_CWO;  p += LL * S_CWO;
      t_w1   = p + l * S_W1;   p += LL * S_W1;
      t_w2   = p + l * S_W2;
    } else {
      u16* p = base;
      t_wq = p;   p += S_WQ;
      t_wkv = p;  p += S_WKV;
      t_wo = p;   p += S_WO;
      t_cwq = p;  p += S_CWQ;
      t_cwkv = p; p += S_CWKV;
      t_cwo = p;  p += S_CWO;
      t_w1 = p;   p += S_W1;
      t_w2 = p;
      // convert this layer's weights
      wtrans_kernel<<<dim3(16, 16, 1), b256, 0, stream>>>(sa_wq  + (size_t)l * S_WQ,   t_wq, 512, 512);
      wtrans_kernel<<<dim3(4, 16, 1),  b256, 0, stream>>>(sa_wkv + (size_t)l * S_WKV,  t_wkv, 512, 128);
      wtrans_kernel<<<dim3(16, 16, 1), b256, 0, stream>>>(sa_wo  + (size_t)l * S_WO,   t_wo, 512, 512);
      wtrans_kernel<<<dim3(16, 16, 1), b256, 0, stream>>>(ca_wq  + (size_t)l * S_CWQ,  t_cwq, 512, 512);
      wtrans_kernel<<<dim3(4, 8, 1),   b256, 0, stream>>>(ca_wkv + (size_t)l * S_CWKV, t_cwkv, 256, 128);
      wtrans_kernel<<<dim3(16, 16, 1), b256, 0, stream>>>(ca_wo  + (size_t)l * S_CWO,  t_cwo, 512, 512);
      wtrans_kernel<<<dim3(128, 16, 1),b256, 0, stream>>>(ff_w1  + (size_t)l * S_W1,   t_w1, 512, 4096);
      wtrans_kernel<<<dim3(16, 64, 1), b256, 0, stream>>>(ff_w2  + (size_t)l * S_W2,   t_w2, 2048, 512);
    }

    // ---- self attention ----
    ln_kernel<<<ROWS, b256, 0, stream>>>(x_cur, l_sa_norm, nullptr, xn_bf, DD, 0, 1);
    mfma_gemm<128, 128, 0><<<dim3(4, 32), b256, 0, stream>>>(xn_bf, t_wq, qlin, nullptr, 4096, 512, 512);
    qprep_kernel<<<8192, b256, 0, stream>>>(qlin, qbuf, 1);
    mfma_gemm<64, 64, 0><<<dim3(2, 64), b256, 0, stream>>>(xn_bf, t_wkv, kvlin, nullptr, 4096, 128, 512);
    kvprep_kernel<<<1025, b256, 0, stream>>>(kvlin, l_sa_null, kbuf, vbuf, 1025, 1024, 1);
    attn_tile_kernel<<<attn_grid, b256, 0, stream>>>(qbuf, kbuf, vbuf, rel_emb, big_bf, 1025, 1, 1);
    mfma_gemm<128, 128, 0><<<dim3(4, 32), b256, 0, stream>>>(big_bf, t_wo, qlin, nullptr, 4096, 512, 512);
    ln_kernel<<<ROWS, b256, 0, stream>>>(qlin, l_sa_outg, x_cur, x_cur, DD, 0, 0);

    // ---- cross attention ----
    ln_kernel<<<ROWS, b256, 0, stream>>>(x_cur, l_ca_norm, nullptr, xn_bf, DD, 0, 1);
    ln_kernel<<<BB * MM, b256, 0, stream>>>(in_ctx, l_ca_ctxg, nullptr, ctxn_bf, PP, 0, 1);
    mfma_gemm<128, 128, 0><<<dim3(4, 32), b256, 0, stream>>>(xn_bf, t_cwq, qlin, nullptr, 4096, 512, 512);
    qprep_kernel<<<8192, b256, 0, stream>>>(qlin, qbuf, 0);
    mfma_gemm<64, 64, 0><<<dim3(2, 32), b256, 0, stream>>>(ctxn_bf, t_cwkv, kvlin, nullptr, 2048, 128, 256);
    kvprep_kernel<<<513, b256, 0, stream>>>(kvlin, l_ca_null, kbuf, vbuf, 513, 512, 0);
    attn_tile_kernel<<<attn_grid, b256, 0, stream>>>(qbuf, kbuf, vbuf, nullptr, big_bf, 513, 0, 0);
    mfma_gemm<128, 128, 0><<<dim3(4, 32), b256, 0, stream>>>(big_bf, t_cwo, qlin, nullptr, 4096, 512, 512);
    ln_kernel<<<ROWS, b256, 0, stream>>>(qlin, l_ca_outg, x_cur, x_cur, DD, 0, 0);

    // ---- feed forward ----
    ln_kernel<<<ROWS, b256, 0, stream>>>(x_cur, l_ff_norm, nullptr, xn_bf, DD, 0, 1);
    mfma_gemm_gated<<<dim3(32, 32), b256, 0, stream>>>(xn_bf, t_w1, ffh, 4096, 2048, 512);
    mfma_gemm<128, 128, 1><<<dim3(4, 32), b256, 0, stream>>>(ffh, t_w2, x_cur, x_cur, 4096, 512, 2048);
  }

  // final stable layernorm, in-place into d_out
  ln_kernel<<<ROWS, b256, 0, stream>>>(x_cur, norm_g, nullptr, x_cur, DD, 1, 0);
}

// Round 4
// 2026.662 us; speedup vs baseline: 6.7688x; 1.7734x over previous
//
#include <hip/hip_runtime.h>
#include <hip/hip_bf16.h>
#include <math.h>

// Problem constants
#define BB 4
#define NN 1024
#define MM 512
#define DD 512
#define PP 256
#define HH 8
#define DHH 64
#define LL 6
#define FFI 2048

typedef unsigned short u16;
typedef __attribute__((ext_vector_type(8))) short frag8;   // 8 bf16 (4 VGPRs)
typedef __attribute__((ext_vector_type(4))) float f32x4;   // MFMA C/D

__device__ __forceinline__ u16 f2bf(float f) {
  union { float f; unsigned u; } x; x.f = f;
  unsigned u = x.u;
  return (u16)((u + 0x7FFFu + ((u >> 16) & 1u)) >> 16);
}

// ---------------------------------------------------------------------------
// LayerNorm: y[row] = LN(x[row]) * g (+ resid[row]); obf => write bf16
// ---------------------------------------------------------------------------
__global__ __launch_bounds__(256) void ln_kernel(const float* __restrict__ x,
                                                 const float* __restrict__ g,
                                                 const float* __restrict__ resid,
                                                 void* __restrict__ y,
                                                 int cols, int stable, int obf) {
  __shared__ float sbuf[8];
  int row = blockIdx.x;
  const float* xr = x + (size_t)row * cols;
  int tid = threadIdx.x;

  float inv_mx = 1.f;
  if (stable) {
    float mx = -INFINITY;
    for (int c = tid; c < cols; c += 256) mx = fmaxf(mx, xr[c]);
    #pragma unroll
    for (int o = 32; o > 0; o >>= 1) mx = fmaxf(mx, __shfl_xor(mx, o));
    if ((tid & 63) == 0) sbuf[tid >> 6] = mx;
    __syncthreads();
    mx = fmaxf(fmaxf(sbuf[0], sbuf[1]), fmaxf(sbuf[2], sbuf[3]));
    __syncthreads();
    inv_mx = 1.f / mx;
  }

  float sum = 0.f, ss = 0.f;
  for (int c = tid; c < cols; c += 256) {
    float v = xr[c] * inv_mx;
    sum += v; ss += v * v;
  }
  #pragma unroll
  for (int o = 32; o > 0; o >>= 1) { sum += __shfl_xor(sum, o); ss += __shfl_xor(ss, o); }
  if ((tid & 63) == 0) { sbuf[tid >> 6] = sum; sbuf[4 + (tid >> 6)] = ss; }
  __syncthreads();
  sum = sbuf[0] + sbuf[1] + sbuf[2] + sbuf[3];
  ss  = sbuf[4] + sbuf[5] + sbuf[6] + sbuf[7];

  float mean = sum / cols;
  float var  = ss / cols - mean * mean;
  float r = rsqrtf(var + 1e-5f);
  for (int c = tid; c < cols; c += 256) {
    float v = (xr[c] * inv_mx - mean) * r * g[c];
    if (resid) v += resid[(size_t)row * cols + c];
    if (obf) ((u16*)y)[(size_t)row * cols + c] = f2bf(v);
    else     ((float*)y)[(size_t)row * cols + c] = v;
  }
}

// ---------------------------------------------------------------------------
// Weight convert + transpose: W (K x N fp32, layer stride K*N) -> Wt (N x K bf16)
// ---------------------------------------------------------------------------
__global__ __launch_bounds__(256) void wtrans_kernel(const float* __restrict__ W,
                                                     u16* __restrict__ Wt,
                                                     int K, int N) {
  __shared__ float tile[32][33];
  size_t lofs = (size_t)blockIdx.z * K * N;
  const float* Wl = W + lofs;
  u16* Wtl = Wt + lofs;
  int n0 = blockIdx.x * 32, k0 = blockIdx.y * 32;
  int t = threadIdx.x;
  #pragma unroll
  for (int it = 0; it < 4; it++) {
    int idx = t + it * 256;
    int r = idx >> 5, c = idx & 31;
    tile[r][c] = Wl[(size_t)(k0 + r) * N + n0 + c];
  }
  __syncthreads();
  #pragma unroll
  for (int it = 0; it < 4; it++) {
    int idx = t + it * 256;
    int r = idx >> 5, c = idx & 31;
    Wtl[(size_t)(n0 + r) * K + k0 + c] = f2bf(tile[c][r]);
  }
}

// ---------------------------------------------------------------------------
// bf16 MFMA GEMM: C(MxN) = A(MxK,bf16) @ Bt(NxK,bf16)^T  [+ res fp32]
// ---------------------------------------------------------------------------
#define LSTR 40

template<int TM, int TN, int RES>
__global__ __launch_bounds__(256) void mfma_gemm(const u16* __restrict__ A,
                                                 const u16* __restrict__ Bt,
                                                 float* __restrict__ C,
                                                 const float* __restrict__ res,
                                                 int M, int N, int K) {
  constexpr int TM2 = TM / 2, TN2 = TN / 2;
  constexpr int IT = TM2 / 16, JT = TN2 / 16;
  constexpr int ASLOT = TM * 4 / 256, BSLOT = TN * 4 / 256;
  __shared__ u16 As[TM * LSTR];
  __shared__ u16 Bs[TN * LSTR];
  int t = threadIdx.x;
  int w = t >> 6, lane = t & 63;
  int bm = blockIdx.y * TM, bn = blockIdx.x * TN;
  int wr = (w >> 1) * TM2, wc = (w & 1) * TN2;
  int lm = lane & 15, q = lane >> 4;

  f32x4 acc[IT][JT] = {};

  for (int k0 = 0; k0 < K; k0 += 32) {
    __syncthreads();
    #pragma unroll
    for (int i = 0; i < ASLOT; i++) {
      int s = t + i * 256; int m = s >> 2, c = s & 3;
      uint4 d = *(const uint4*)(A + (size_t)(bm + m) * K + k0 + c * 8);
      *(uint4*)&As[m * LSTR + c * 8] = d;
    }
    #pragma unroll
    for (int i = 0; i < BSLOT; i++) {
      int s = t + i * 256; int n = s >> 2, c = s & 3;
      uint4 d = *(const uint4*)(Bt + (size_t)(bn + n) * K + k0 + c * 8);
      *(uint4*)&Bs[n * LSTR + c * 8] = d;
    }
    __syncthreads();
    frag8 a[IT], b[JT];
    #pragma unroll
    for (int i = 0; i < IT; i++) a[i] = *(const frag8*)&As[(wr + i * 16 + lm) * LSTR + q * 8];
    #pragma unroll
    for (int j = 0; j < JT; j++) b[j] = *(const frag8*)&Bs[(wc + j * 16 + lm) * LSTR + q * 8];
    #pragma unroll
    for (int i = 0; i < IT; i++)
      #pragma unroll
      for (int j = 0; j < JT; j++)
        acc[i][j] = __builtin_amdgcn_mfma_f32_16x16x32_bf16(a[i], b[j], acc[i][j], 0, 0, 0);
  }

  #pragma unroll
  for (int i = 0; i < IT; i++)
    #pragma unroll
    for (int j = 0; j < JT; j++)
      #pragma unroll
      for (int r = 0; r < 4; r++) {
        int row = bm + wr + i * 16 + q * 4 + r;
        int col = bn + wc + j * 16 + lm;
        float v = acc[i][j][r];
        if (RES) v += res[(size_t)row * N + col];
        C[(size_t)row * N + col] = v;
      }
}

// ---------------------------------------------------------------------------
// Gated FF MFMA GEMM: Bt is (2*FI) x K; out C(M x FI, bf16) = h * silu(gate)
// ---------------------------------------------------------------------------
__global__ __launch_bounds__(256) void mfma_gemm_gated(const u16* __restrict__ A,
                                                       const u16* __restrict__ Bt,
                                                       u16* __restrict__ C,
                                                       int M, int FI, int K) {
  constexpr int TM = 128, TN = 64;
  constexpr int TM2 = 64, TN2 = 32;
  constexpr int IT = 4, JT = 2;
  __shared__ u16 As[TM * LSTR];
  __shared__ u16 Bh[TN * LSTR];
  __shared__ u16 Bg[TN * LSTR];
  int t = threadIdx.x;
  int w = t >> 6, lane = t & 63;
  int bm = blockIdx.y * TM, bn = blockIdx.x * TN;
  int wr = (w >> 1) * TM2, wc = (w & 1) * TN2;
  int lm = lane & 15, q = lane >> 4;

  f32x4 ah[IT][JT] = {};
  f32x4 ag[IT][JT] = {};

  for (int k0 = 0; k0 < K; k0 += 32) {
    __syncthreads();
    #pragma unroll
    for (int i = 0; i < 2; i++) {
      int s = t + i * 256; int m = s >> 2, c = s & 3;
      uint4 d = *(const uint4*)(A + (size_t)(bm + m) * K + k0 + c * 8);
      *(uint4*)&As[m * LSTR + c * 8] = d;
    }
    {
      int s = t; int n = s >> 2, c = s & 3;
      uint4 dh = *(const uint4*)(Bt + (size_t)(bn + n) * K + k0 + c * 8);
      uint4 dg = *(const uint4*)(Bt + (size_t)(bn + FI + n) * K + k0 + c * 8);
      *(uint4*)&Bh[n * LSTR + c * 8] = dh;
      *(uint4*)&Bg[n * LSTR + c * 8] = dg;
    }
    __syncthreads();
    frag8 a[IT], bh[JT], bg[JT];
    #pragma unroll
    for (int i = 0; i < IT; i++) a[i] = *(const frag8*)&As[(wr + i * 16 + lm) * LSTR + q * 8];
    #pragma unroll
    for (int j = 0; j < JT; j++) {
      bh[j] = *(const frag8*)&Bh[(wc + j * 16 + lm) * LSTR + q * 8];
      bg[j] = *(const frag8*)&Bg[(wc + j * 16 + lm) * LSTR + q * 8];
    }
    #pragma unroll
    for (int i = 0; i < IT; i++)
      #pragma unroll
      for (int j = 0; j < JT; j++) {
        ah[i][j] = __builtin_amdgcn_mfma_f32_16x16x32_bf16(a[i], bh[j], ah[i][j], 0, 0, 0);
        ag[i][j] = __builtin_amdgcn_mfma_f32_16x16x32_bf16(a[i], bg[j], ag[i][j], 0, 0, 0);
      }
  }

  #pragma unroll
  for (int i = 0; i < IT; i++)
    #pragma unroll
    for (int j = 0; j < JT; j++)
      #pragma unroll
      for (int r = 0; r < 4; r++) {
        int row = bm + wr + i * 16 + q * 4 + r;
        int col = bn + wc + j * 16 + lm;
        float h = ah[i][j][r], g = ag[i][j][r];
        float sg = 1.f / (1.f + __expf(-g));
        C[(size_t)row * FI + col] = f2bf(h * g * sg);
      }
}

// ---------------------------------------------------------------------------
// Bias table: tab[h][delta] = rel_emb[bucket(delta)][h], delta in [0,1024)
// ---------------------------------------------------------------------------
__global__ __launch_bounds__(256) void biasprep_kernel(const float* __restrict__ rel_emb,
                                                       float* __restrict__ tab) {
  int idx = blockIdx.x * 256 + threadIdx.x;   // 8192
  int h = idx >> 10, delta = idx & 1023;
  int bucket;
  if (delta < 16) bucket = delta;
  else {
    bucket = 16 + (int)(__logf((float)delta * (1.f / 16.f)) * (16.f / 2.0794415416798357f));
    if (bucket > 31) bucket = 31;
  }
  tab[idx] = rel_emb[bucket * HH + h];
}

// ---------------------------------------------------------------------------
// Q prep: qbf[b][h][i][d] = bf16(rotary?(q_lin[b][i][h*64+d] * 0.125))
// ---------------------------------------------------------------------------
__global__ __launch_bounds__(256) void qprep_kernel(const float* __restrict__ q_lin,
                                                    u16* __restrict__ q, int use_rot) {
  int idx = blockIdx.x * 256 + threadIdx.x;   // ((b*8+h)*1024+i)*64+d
  int d = idx & 63;
  int i = (idx >> 6) & 1023;
  int h = (idx >> 16) & 7;
  int b = idx >> 19;
  const float* src = q_lin + ((size_t)(b * NN + i)) * DD + h * DHH;
  float val = src[d] * 0.125f;
  if (use_rot && d < 32) {
    int dd = d & 15;
    float inv = powf(10000.f, -(float)dd * (1.f / 16.f));
    float a = (float)i * inv;
    float other = src[(d < 16) ? d + 16 : d - 16] * 0.125f;
    val = val * cosf(a) + ((d < 16) ? -other : other) * sinf(a);
  }
  q[idx] = f2bf(val);
}

// ---------------------------------------------------------------------------
// KV prep: k (b, NKS, 64) bf16 rows (zero-pad j>=NK); vt (b, 64, NKS) bf16.
// null kv at j=0; rotary on k (self-attn only). grid covers B*NKS*64/256.
// ---------------------------------------------------------------------------
__global__ __launch_bounds__(256) void kvprep_kernel(const float* __restrict__ kv_lin,
                                                     const float* __restrict__ null_kv,
                                                     u16* __restrict__ k, u16* __restrict__ vt,
                                                     int NK, int NKS, int NT, int use_rot) {
  int idx = blockIdx.x * 256 + threadIdx.x;
  int d = idx & 63;
  int rem = idx >> 6;
  int j = rem % NKS;
  int b = rem / NKS;
  float kval = 0.f, vval = 0.f;
  if (j == 0) {
    kval = null_kv[d];
    vval = null_kv[64 + d];
  } else if (j < NK) {
    int t = j - 1;
    const float* src = kv_lin + ((size_t)(b * NT + t)) * 128;
    kval = src[d];
    vval = src[64 + d];
    if (use_rot && d < 32) {
      int dd = d & 15;
      float inv = powf(10000.f, -(float)dd * (1.f / 16.f));
      float a = (float)t * inv;
      float other = src[(d < 16) ? d + 16 : d - 16];
      kval = kval * cosf(a) + ((d < 16) ? -other : other) * sinf(a);
    }
  }
  k[((size_t)b * NKS + j) * 64 + d] = f2bf(kval);
  vt[((size_t)b * 64 + d) * NKS + j] = f2bf(vval);
}

// ---------------------------------------------------------------------------
// MFMA flash attention. Block = 256 thr = 4 waves; TQ=64 (16 q-rows/wave),
// TK=64 keys/tile. QK^T + PV via mfma_f32_16x16x32_bf16; online softmax in
// C-layout registers; P->A-layout via wave-private LDS round-trip.
// q: (B,H,N,64) bf16; k: (B,NKS,64) bf16; vt: (B,64,NKS) bf16; out (B,N,512) bf16
// ---------------------------------------------------------------------------
#define AT_STR 72

__global__ __launch_bounds__(256) void attn_mfma_kernel(
    const u16* __restrict__ q,
    const u16* __restrict__ kbuf,
    const u16* __restrict__ vtbuf,
    const float* __restrict__ bias_tab,
    u16* __restrict__ out,
    int n_keys, int NKS, int causal, int use_bias) {
  __shared__ u16 Ks[64 * AT_STR];
  __shared__ u16 Vts[64 * AT_STR];
  __shared__ u16 Sts[64 * AT_STR];
  __shared__ float bias_s[1024];

  int t = threadIdx.x;
  int wv = t >> 6, lane = t & 63;
  int lm = lane & 15, qd = lane >> 4;
  int bh = blockIdx.y;
  int b = bh >> 3, h = bh & 7;
  int i0 = blockIdx.x * 64;
  int wbase = wv * 16;

  if (use_bias) {
    *(float4*)&bias_s[t * 4] = *(const float4*)(bias_tab + h * 1024 + t * 4);
  }

  // Q fragments (A-layout): lane m=lm holds rows i0+wbase+lm, k = qd*8+j (+32)
  frag8 qf0, qf1;
  {
    const u16* qrow = q + ((size_t)bh * NN + i0 + wbase + lm) * 64 + qd * 8;
    qf0 = *(const frag8*)(qrow);
    qf1 = *(const frag8*)(qrow + 32);
  }

  float m_r[4], l_r[4];
  #pragma unroll
  for (int r = 0; r < 4; r++) { m_r[r] = -1e30f; l_r[r] = 0.f; }
  f32x4 of[4] = {};

  int num_t = causal ? (blockIdx.x + 2) : ((n_keys + 63) / 64);
  const u16* kb  = kbuf  + (size_t)b * NKS * 64;
  const u16* vtb = vtbuf + (size_t)b * 64 * NKS;

  for (int tile = 0; tile < num_t; tile++) {
    int j0 = tile * 64;
    __syncthreads();
    // stage K (64x64) and Vt (64x64) tiles: 512 uint4 pieces each
    #pragma unroll
    for (int it = 0; it < 2; it++) {
      int pc = t + it * 256;
      int row = pc >> 3, seg = pc & 7;
      *(uint4*)&Ks[row * AT_STR + seg * 8] =
          *(const uint4*)(kb + (size_t)(j0 + row) * 64 + seg * 8);
      *(uint4*)&Vts[row * AT_STR + seg * 8] =
          *(const uint4*)(vtb + (size_t)row * NKS + j0 + seg * 8);
    }
    __syncthreads();

    // ---- scores S = Q K^T : 4 key-fragments x 2 k-steps ----
    f32x4 sf[4];
    #pragma unroll
    for (int jf = 0; jf < 4; jf++) {
      frag8 kf0 = *(const frag8*)&Ks[(jf * 16 + lm) * AT_STR + qd * 8];
      frag8 kf1 = *(const frag8*)&Ks[(jf * 16 + lm) * AT_STR + 32 + qd * 8];
      f32x4 sa = {};
      sa = __builtin_amdgcn_mfma_f32_16x16x32_bf16(qf0, kf0, sa, 0, 0, 0);
      sa = __builtin_amdgcn_mfma_f32_16x16x32_bf16(qf1, kf1, sa, 0, 0, 0);
      sf[jf] = sa;
    }

    // ---- bias + mask; tile row-max ----
    float sv[4][4];   // [jf][r]
    float tmax[4] = {-1e30f, -1e30f, -1e30f, -1e30f};
    #pragma unroll
    for (int jf = 0; jf < 4; jf++) {
      int gj = j0 + jf * 16 + lm;
      #pragma unroll
      for (int r = 0; r < 4; r++) {
        int gi = i0 + wbase + qd * 4 + r;
        float val = sf[jf][r];
        if (use_bias) {
          int nd = gi - gj; nd = nd < 0 ? 0 : nd;
          val += bias_s[nd];
        }
        bool bad = (gj >= n_keys) || (causal && gj > gi + 1);
        val = bad ? -1e30f : val;
        sv[jf][r] = val;
        tmax[r] = fmaxf(tmax[r], val);
      }
    }
    #pragma unroll
    for (int r = 0; r < 4; r++) {
      tmax[r] = fmaxf(tmax[r], __shfl_xor(tmax[r], 1));
      tmax[r] = fmaxf(tmax[r], __shfl_xor(tmax[r], 2));
      tmax[r] = fmaxf(tmax[r], __shfl_xor(tmax[r], 4));
      tmax[r] = fmaxf(tmax[r], __shfl_xor(tmax[r], 8));
    }

    // ---- online softmax update ----
    float alpha[4], rsum[4];
    #pragma unroll
    for (int r = 0; r < 4; r++) {
      float mn = fmaxf(m_r[r], tmax[r]);
      alpha[r] = __expf(m_r[r] - mn);
      m_r[r] = mn;
      rsum[r] = 0.f;
    }
    #pragma unroll
    for (int jf = 0; jf < 4; jf++) {
      #pragma unroll
      for (int r = 0; r < 4; r++) {
        float p = __expf(sv[jf][r] - m_r[r]);
        rsum[r] += p;
        Sts[(wbase + qd * 4 + r) * AT_STR + jf * 16 + lm] = f2bf(p);
      }
    }
    #pragma unroll
    for (int r = 0; r < 4; r++) {
      rsum[r] += __shfl_xor(rsum[r], 1);
      rsum[r] += __shfl_xor(rsum[r], 2);
      rsum[r] += __shfl_xor(rsum[r], 4);
      rsum[r] += __shfl_xor(rsum[r], 8);
      l_r[r] = l_r[r] * alpha[r] + rsum[r];
    }

    // ---- O = O*alpha + P V ----
    frag8 pf0 = *(const frag8*)&Sts[(wbase + lm) * AT_STR + qd * 8];
    frag8 pf1 = *(const frag8*)&Sts[(wbase + lm) * AT_STR + 32 + qd * 8];
    #pragma unroll
    for (int nf = 0; nf < 4; nf++) {
      f32x4 oc = of[nf];
      oc[0] *= alpha[0]; oc[1] *= alpha[1]; oc[2] *= alpha[2]; oc[3] *= alpha[3];
      frag8 vf0 = *(const frag8*)&Vts[(nf * 16 + lm) * AT_STR + qd * 8];
      frag8 vf1 = *(const frag8*)&Vts[(nf * 16 + lm) * AT_STR + 32 + qd * 8];
      oc = __builtin_amdgcn_mfma_f32_16x16x32_bf16(pf0, vf0, oc, 0, 0, 0);
      oc = __builtin_amdgcn_mfma_f32_16x16x32_bf16(pf1, vf1, oc, 0, 0, 0);
      of[nf] = oc;
    }
  }

  // ---- epilogue: normalize, write (B,N,H*64) bf16 ----
  float invl[4];
  #pragma unroll
  for (int r = 0; r < 4; r++) invl[r] = 1.f / l_r[r];
  #pragma unroll
  for (int nf = 0; nf < 4; nf++)
    #pragma unroll
    for (int r = 0; r < 4; r++) {
      int gi = i0 + wbase + qd * 4 + r;
      out[((size_t)(b * NN + gi)) * DD + h * 64 + nf * 16 + lm] = f2bf(of[nf][r] * invl[r]);
    }
}

// ---------------------------------------------------------------------------
// Orchestration
// ---------------------------------------------------------------------------
extern "C" void kernel_launch(void* const* d_in, const int* in_sizes, int n_in,
                              void* d_out, int out_size, void* d_ws, size_t ws_size,
                              hipStream_t stream) {
  const float* in_x      = (const float*)d_in[0];
  const float* in_ctx    = (const float*)d_in[1];
  const float* rel_emb   = (const float*)d_in[2];
  const float* sa_norm_g = (const float*)d_in[3];
  const float* sa_wq     = (const float*)d_in[4];
  const float* sa_wkv    = (const float*)d_in[5];
  const float* sa_nullkv = (const float*)d_in[6];
  const float* sa_wo     = (const float*)d_in[7];
  const float* sa_out_g  = (const float*)d_in[8];
  const float* ca_norm_g = (const float*)d_in[9];
  const float* ca_ctx_g  = (const float*)d_in[10];
  const float* ca_wq     = (const float*)d_in[11];
  const float* ca_wkv    = (const float*)d_in[12];
  const float* ca_nullkv = (const float*)d_in[13];
  const float* ca_wo     = (const float*)d_in[14];
  const float* ca_out_g  = (const float*)d_in[15];
  const float* ff_norm_g = (const float*)d_in[16];
  const float* ff_w1     = (const float*)d_in[17];
  const float* ff_w2     = (const float*)d_in[18];
  const float* norm_g    = (const float*)d_in[19];

  const size_t XSZ = (size_t)BB * NN * DD;   // 2,097,152
  const int NKS_SA = 1088;                   // 17 tiles * 64
  const int NKS_CA = 576;                    // 9 tiles * 64

  float* x_cur = (float*)d_out;

  char* p = (char*)d_ws;
  float* qlin     = (float*)p;  p += XSZ * 4;                  // 8 MB
  float* kvlin    = (float*)p;  p += (size_t)524288 * 4;       // 2 MB
  float* bias_tab = (float*)p;  p += 8192 * 4;                 // 32 KB
  u16* xn_bf   = (u16*)p;  p += XSZ * 2;                       // 4 MB
  u16* ctxn_bf = (u16*)p;  p += (size_t)524288 * 2;            // 1 MB
  u16* big_bf  = (u16*)p;  p += XSZ * 2;                       // 4 MB
  u16* ffh     = (u16*)p;  p += (size_t)8388608 * 2;           // 16 MB
  u16* qbf     = (u16*)p;  p += XSZ * 2;                       // 4 MB
  u16* kbf     = (u16*)p;  p += (size_t)BB * NKS_SA * 64 * 2;  // 557 KB
  u16* vtbf    = (u16*)p;  p += (size_t)BB * NKS_SA * 64 * 2;  // 557 KB
  u16* wreg    = (u16*)p;

  const size_t S_WQ = 512 * 512, S_WKV = 512 * 128, S_WO = 512 * 512;
  const size_t S_CWQ = 512 * 512, S_CWKV = 256 * 128, S_CWO = 512 * 512;
  const size_t S_W1 = 512 * 4096, S_W2 = 2048 * 512;
  const size_t S_LAYER = S_WQ + S_WKV + S_WO + S_CWQ + S_CWKV + S_CWO + S_W1 + S_W2;

  const size_t base_bytes = (size_t)((char*)wreg - (char*)d_ws);
  const size_t need_all = base_bytes + (size_t)LL * S_LAYER * 2;
  const int all_mode = (ws_size >= need_all) ? 1 : 0;

  dim3 b256(256);

  biasprep_kernel<<<32, b256, 0, stream>>>(rel_emb, bias_tab);

  if (all_mode) {
    u16* pw = wreg;
    wtrans_kernel<<<dim3(16, 16, LL), b256, 0, stream>>>(sa_wq,  pw, 512, 512);  pw += LL * S_WQ;
    wtrans_kernel<<<dim3(4, 16, LL),  b256, 0, stream>>>(sa_wkv, pw, 512, 128);  pw += LL * S_WKV;
    wtrans_kernel<<<dim3(16, 16, LL), b256, 0, stream>>>(sa_wo,  pw, 512, 512);  pw += LL * S_WO;
    wtrans_kernel<<<dim3(16, 16, LL), b256, 0, stream>>>(ca_wq,  pw, 512, 512);  pw += LL * S_CWQ;
    wtrans_kernel<<<dim3(4, 8, LL),   b256, 0, stream>>>(ca_wkv, pw, 256, 128);  pw += LL * S_CWKV;
    wtrans_kernel<<<dim3(16, 16, LL), b256, 0, stream>>>(ca_wo,  pw, 512, 512);  pw += LL * S_CWO;
    wtrans_kernel<<<dim3(128, 16, LL),b256, 0, stream>>>(ff_w1,  pw, 512, 4096); pw += LL * S_W1;
    wtrans_kernel<<<dim3(16, 64, LL), b256, 0, stream>>>(ff_w2,  pw, 2048, 512);
  }

  hipMemcpyAsync(x_cur, in_x, sizeof(float) * XSZ, hipMemcpyDeviceToDevice, stream);

  const int ROWS = BB * NN;                  // 4096
  dim3 attn_grid(NN / 64, BB * HH);          // (16, 32)

  for (int l = 0; l < LL; l++) {
    const float* l_sa_norm = sa_norm_g + l * DD;
    const float* l_sa_null = sa_nullkv + l * 2 * DHH;
    const float* l_sa_outg = sa_out_g + l * DD;
    const float* l_ca_norm = ca_norm_g + l * DD;
    const float* l_ca_ctxg = ca_ctx_g + l * PP;
    const float* l_ca_null = ca_nullkv + l * 2 * DHH;
    const float* l_ca_outg = ca_out_g + l * DD;
    const float* l_ff_norm = ff_norm_g + l * DD;

    u16 *t_wq, *t_wkv, *t_wo, *t_cwq, *t_cwkv, *t_cwo, *t_w1, *t_w2;
    if (all_mode) {
      u16* pw = wreg;
      t_wq   = pw + l * S_WQ;   pw += LL * S_WQ;
      t_wkv  = pw + l * S_WKV;  pw += LL * S_WKV;
      t_wo   = pw + l * S_WO;   pw += LL * S_WO;
      t_cwq  = pw + l * S_CWQ;  pw += LL * S_CWQ;
      t_cwkv = pw + l * S_CWKV; pw += LL * S_CWKV;
      t_cwo  = pw + l * S_CWO;  pw += LL * S_CWO;
      t_w1   = pw + l * S_W1;   pw += LL * S_W1;
      t_w2   = pw + l * S_W2;
    } else {
      u16* pw = wreg;
      t_wq = pw;   pw += S_WQ;
      t_wkv = pw;  pw += S_WKV;
      t_wo = pw;   pw += S_WO;
      t_cwq = pw;  pw += S_CWQ;
      t_cwkv = pw; pw += S_CWKV;
      t_cwo = pw;  pw += S_CWO;
      t_w1 = pw;   pw += S_W1;
      t_w2 = pw;
      wtrans_kernel<<<dim3(16, 16, 1), b256, 0, stream>>>(sa_wq  + (size_t)l * S_WQ,   t_wq, 512, 512);
      wtrans_kernel<<<dim3(4, 16, 1),  b256, 0, stream>>>(sa_wkv + (size_t)l * S_WKV,  t_wkv, 512, 128);
      wtrans_kernel<<<dim3(16, 16, 1), b256, 0, stream>>>(sa_wo  + (size_t)l * S_WO,   t_wo, 512, 512);
      wtrans_kernel<<<dim3(16, 16, 1), b256, 0, stream>>>(ca_wq  + (size_t)l * S_CWQ,  t_cwq, 512, 512);
      wtrans_kernel<<<dim3(4, 8, 1),   b256, 0, stream>>>(ca_wkv + (size_t)l * S_CWKV, t_cwkv, 256, 128);
      wtrans_kernel<<<dim3(16, 16, 1), b256, 0, stream>>>(ca_wo  + (size_t)l * S_CWO,  t_cwo, 512, 512);
      wtrans_kernel<<<dim3(128, 16, 1),b256, 0, stream>>>(ff_w1  + (size_t)l * S_W1,   t_w1, 512, 4096);
      wtrans_kernel<<<dim3(16, 64, 1), b256, 0, stream>>>(ff_w2  + (size_t)l * S_W2,   t_w2, 2048, 512);
    }

    // ---- self attention ----
    ln_kernel<<<ROWS, b256, 0, stream>>>(x_cur, l_sa_norm, nullptr, xn_bf, DD, 0, 1);
    mfma_gemm<128, 128, 0><<<dim3(4, 32), b256, 0, stream>>>(xn_bf, t_wq, qlin, nullptr, 4096, 512, 512);
    qprep_kernel<<<8192, b256, 0, stream>>>(qlin, qbf, 1);
    mfma_gemm<64, 64, 0><<<dim3(2, 64), b256, 0, stream>>>(xn_bf, t_wkv, kvlin, nullptr, 4096, 128, 512);
    kvprep_kernel<<<BB * NKS_SA / 4, b256, 0, stream>>>(kvlin, l_sa_null, kbf, vtbf, 1025, NKS_SA, 1024, 1);
    attn_mfma_kernel<<<attn_grid, b256, 0, stream>>>(qbf, kbf, vtbf, bias_tab, big_bf, 1025, NKS_SA, 1, 1);
    mfma_gemm<128, 128, 0><<<dim3(4, 32), b256, 0, stream>>>(big_bf, t_wo, qlin, nullptr, 4096, 512, 512);
    ln_kernel<<<ROWS, b256, 0, stream>>>(qlin, l_sa_outg, x_cur, x_cur, DD, 0, 0);

    // ---- cross attention ----
    ln_kernel<<<ROWS, b256, 0, stream>>>(x_cur, l_ca_norm, nullptr, xn_bf, DD, 0, 1);
    ln_kernel<<<BB * MM, b256, 0, stream>>>(in_ctx, l_ca_ctxg, nullptr, ctxn_bf, PP, 0, 1);
    mfma_gemm<128, 128, 0><<<dim3(4, 32), b256, 0, stream>>>(xn_bf, t_cwq, qlin, nullptr, 4096, 512, 512);
    qprep_kernel<<<8192, b256, 0, stream>>>(qlin, qbf, 0);
    mfma_gemm<64, 64, 0><<<dim3(2, 32), b256, 0, stream>>>(ctxn_bf, t_cwkv, kvlin, nullptr, 2048, 128, 256);
    kvprep_kernel<<<BB * NKS_CA / 4, b256, 0, stream>>>(kvlin, l_ca_null, kbf, vtbf, 513, NKS_CA, 512, 0);
    attn_mfma_kernel<<<attn_grid, b256, 0, stream>>>(qbf, kbf, vtbf, nullptr, big_bf, 513, NKS_CA, 0, 0);
    mfma_gemm<128, 128, 0><<<dim3(4, 32), b256, 0, stream>>>(big_bf, t_cwo, qlin, nullptr, 4096, 512, 512);
    ln_kernel<<<ROWS, b256, 0, stream>>>(qlin, l_ca_outg, x_cur, x_cur, DD, 0, 0);

    // ---- feed forward ----
    ln_kernel<<<ROWS, b256, 0, stream>>>(x_cur, l_ff_norm, nullptr, xn_bf, DD, 0, 1);
    mfma_gemm_gated<<<dim3(32, 32), b256, 0, stream>>>(xn_bf, t_w1, ffh, 4096, 2048, 512);
    mfma_gemm<128, 128, 1><<<dim3(4, 32), b256, 0, stream>>>(ffh, t_w2, x_cur, x_cur, 4096, 512, 2048);
  }

  // final stable layernorm, in-place into d_out
  ln_kernel<<<ROWS, b256, 0, stream>>>(x_cur, norm_g, nullptr, x_cur, DD, 1, 0);
}